// Round 7
// baseline (439.330 us; speedup 1.0000x reference)
//
#include <hip/hip_runtime.h>
#include <hip/hip_fp16.h>
#include <math.h>

// HeteroGNN: 2-layer bipartite single-head GAT (users<->badges).
// R19 (from R18 @430us WIN; megaL1 off the top-5. New top: k_stageA ~100us,
// occupancy 50.7% with LDS_Block_Size 24064 -> 6 blocks/CU cap; VALU 23%,
// HBM 21%, conflicts 4% -> latency-bound from low TLP):
//   - PART_PER 4880 -> 2440: LDS/block ~24KiB -> ~14KiB, blocks/CU 6 -> 8
//     (2048-thread cap, 100% theoretical occupancy). Partition blocks
//     2050 -> 4100 (better interleave + tail). per stays %4==0 (int4 ok).
// Everything else identical to R18 (pair-gather megaL1 w/ alpha-via-dot,
// stageA interleave, int4 edge streams, XCD-pinned shards, packed-float4
// L2 gather w/ 2-stage pipeline).

#define NEG_SLOPE 0.2f
#define PART_PER 2440
#define NBC 196
#define CAPC 27072
#define NHALF 392
#define CAPH 13824
#define SHARD_DIV 50000

__device__ __forceinline__ float lrelu(float x) { return x > 0.f ? x : NEG_SLOPE * x; }

// ---------------- stage A: coarse partition (both graphs) + L1 node transforms ----------------
__global__ void k_stageA(
    const int* __restrict__ src0, const int* __restrict__ dst0,
    const int* __restrict__ src1, const int* __restrict__ dst1,
    int nE, int pblocks, unsigned* __restrict__ part0, unsigned* __restrict__ part1,
    int* __restrict__ bcnt,
    const float* __restrict__ xu, const float* __restrict__ xb,
    const float* __restrict__ Wub_s, const float* __restrict__ aub_s,
    const float* __restrict__ Wbu_d, const float* __restrict__ abu_d,
    const float* __restrict__ Wbu_s, const float* __restrict__ abu_s,
    const float* __restrict__ Wub_d, const float* __restrict__ aub_d,
    __half* __restrict__ hs_u, float* __restrict__ as_u, float* __restrict__ ad_u,
    __half* __restrict__ hs_b, float* __restrict__ as_b, float* __restrict__ ad_b,
    int NU, int NB, int gNU, int partBlocks, int nodeBlocks) {
  union Sm {
    struct { unsigned s_sorted[PART_PER]; int h[257]; int ps[256]; int resb[256]; int cur[256]; } p;
    struct { float sW[64 * 16]; float sa[16]; float sv[64]; } n;
  };
  __shared__ Sm sm;
  int t = threadIdx.x;
  // ---- interleave mapping: 2 partition blocks : 1 node block ----
  int b = blockIdx.x;
  int k = min(nodeBlocks, partBlocks / 2);
  int inter = 3 * k;
  int partIdx = -1, nodeIdx = -1;
  if (b < inter) {
    if ((b % 3) == 2) nodeIdx = b / 3;
    else partIdx = (b / 3) * 2 + (b % 3);
  } else {
    int rem = b - inter;
    int ptail = partBlocks - 2 * k;
    if (rem < ptail) partIdx = 2 * k + rem;
    else nodeIdx = k + (rem - ptail);
  }
  if (partIdx >= 0) {
    // ===== partition branch =====
    int gb = partIdx;
    const int* src; const int* dst; unsigned* part; int* bc; int shift; int mask;
    if (gb < pblocks) { src = src0; dst = dst0; part = part0; bc = bcnt; shift = 8; mask = 255; }
    else { gb -= pblocks; src = src1; dst = dst1; part = part1; bc = bcnt + 256; shift = 10; mask = 1023; }
    int per = (nE + pblocks - 1) / pblocks;
    int beg = gb * per;
    int end = min(beg + per, nE);
    int cnt = end - beg;
    int cnt4 = cnt & ~3;
    sm.p.h[t] = 0;
    __syncthreads();
    // hist: int4 loads (beg 16B-aligned: per % 4 == 0)
    for (int i = beg + t * 4; i + 3 < end; i += 1024) {
      int4 d4 = *(const int4*)(dst + i);
      atomicAdd(&sm.p.h[d4.x >> shift], 1);
      atomicAdd(&sm.p.h[d4.y >> shift], 1);
      atomicAdd(&sm.p.h[d4.z >> shift], 1);
      atomicAdd(&sm.p.h[d4.w >> shift], 1);
    }
    for (int i = beg + cnt4 + t; i < end; i += 256) atomicAdd(&sm.p.h[dst[i] >> shift], 1);
    __syncthreads();
    int v = sm.p.h[t];
    sm.p.ps[t] = v;
    __syncthreads();
    for (int off = 1; off < 256; off <<= 1) {
      int u = (t >= off) ? sm.p.ps[t - off] : 0;
      __syncthreads();
      sm.p.ps[t] += u;
      __syncthreads();
    }
    int excl = sm.p.ps[t] - v;
    sm.p.resb[t] = (t < NBC && v > 0) ? atomicAdd(&bc[t], v) : 0;
    __syncthreads();
    sm.p.h[t] = excl;
    sm.p.cur[t] = excl;
    if (t == 255) sm.p.h[256] = excl + v;
    __syncthreads();
    // scatter: int4 loads of dst+src
    for (int i = beg + t * 4; i + 3 < end; i += 1024) {
      int4 d4 = *(const int4*)(dst + i);
      int4 s4 = *(const int4*)(src + i);
      int r;
      r = atomicAdd(&sm.p.cur[d4.x >> shift], 1);
      sm.p.s_sorted[r] = ((unsigned)(d4.x & mask) << 18) | (unsigned)s4.x;
      r = atomicAdd(&sm.p.cur[d4.y >> shift], 1);
      sm.p.s_sorted[r] = ((unsigned)(d4.y & mask) << 18) | (unsigned)s4.y;
      r = atomicAdd(&sm.p.cur[d4.z >> shift], 1);
      sm.p.s_sorted[r] = ((unsigned)(d4.z & mask) << 18) | (unsigned)s4.z;
      r = atomicAdd(&sm.p.cur[d4.w >> shift], 1);
      sm.p.s_sorted[r] = ((unsigned)(d4.w & mask) << 18) | (unsigned)s4.w;
    }
    for (int i = beg + cnt4 + t; i < end; i += 256) {
      int d = dst[i];
      int r = atomicAdd(&sm.p.cur[d >> shift], 1);
      sm.p.s_sorted[r] = ((unsigned)(d & mask) << 18) | (unsigned)src[i];
    }
    __syncthreads();
    // flush: 4 concurrent binary-search chains per thread (ILP)
    for (int i = t; i < cnt; i += 1024) {
      int i1 = i + 256, i2 = i + 512, i3 = i + 768;
      int lo0 = 0, lo1 = 0, lo2 = 0, lo3 = 0;
      int hi0 = 256, hi1 = 256, hi2 = 256, hi3 = 256;
#pragma unroll
      for (int s = 0; s < 8; ++s) {
        int m0 = (lo0 + hi0) >> 1; if (sm.p.h[m0] <= i)  lo0 = m0; else hi0 = m0;
        int m1 = (lo1 + hi1) >> 1; if (sm.p.h[m1] <= i1) lo1 = m1; else hi1 = m1;
        int m2 = (lo2 + hi2) >> 1; if (sm.p.h[m2] <= i2) lo2 = m2; else hi2 = m2;
        int m3 = (lo3 + hi3) >> 1; if (sm.p.h[m3] <= i3) lo3 = m3; else hi3 = m3;
      }
      { int p = sm.p.resb[lo0] + (i - sm.p.h[lo0]);
        if (p < CAPC) part[(size_t)lo0 * CAPC + p] = sm.p.s_sorted[i]; }
      if (i1 < cnt) { int p = sm.p.resb[lo1] + (i1 - sm.p.h[lo1]);
        if (p < CAPC) part[(size_t)lo1 * CAPC + p] = sm.p.s_sorted[i1]; }
      if (i2 < cnt) { int p = sm.p.resb[lo2] + (i2 - sm.p.h[lo2]);
        if (p < CAPC) part[(size_t)lo2 * CAPC + p] = sm.p.s_sorted[i2]; }
      if (i3 < cnt) { int p = sm.p.resb[lo3] + (i3 - sm.p.h[lo3]);
        if (p < CAPC) part[(size_t)lo3 * CAPC + p] = sm.p.s_sorted[i3]; }
    }
    return;
  }
  // ===== nodes branch =====
  int blk = nodeIdx;
  bool us = blk < gNU;
  const float* x  = us ? xu : xb;
  const float* Ws = us ? Wub_s : Wbu_s;
  const float* As = us ? aub_s : abu_s;
  const float* Wd = us ? Wbu_d : Wub_d;
  const float* Ad = us ? abu_d : aub_d;
  __half* hs = us ? hs_u : hs_b;
  float* als = us ? as_u : as_b;
  float* ald = us ? ad_u : ad_b;
  int N = us ? NU : NB;
  for (int i = t; i < 64 * 16; i += 256) sm.n.sW[i] = Ws[i];
  if (t < 16) sm.n.sa[t] = As[t];
  if (t < 64) {
    float s = 0.f;
    for (int c = 0; c < 16; ++c) s += Wd[t * 16 + c] * Ad[c];
    sm.n.sv[t] = s;
  }
  __syncthreads();
  int n = (us ? blk : blk - gNU) * 256 + t;
  if (n >= N) return;
  float acc[16];
#pragma unroll
  for (int c = 0; c < 16; ++c) acc[c] = 0.f;
  float ad = 0.f;
  const float4* xr4 = (const float4*)(x + (size_t)n * 64);
#pragma unroll 4
  for (int f4 = 0; f4 < 16; ++f4) {
    float4 xv4 = xr4[f4];
    float xv[4] = {xv4.x, xv4.y, xv4.z, xv4.w};
#pragma unroll
    for (int q = 0; q < 4; ++q) {
      int f = f4 * 4 + q;
#pragma unroll
      for (int c = 0; c < 16; ++c) acc[c] += xv[q] * sm.n.sW[f * 16 + c];
      ad += xv[q] * sm.n.sv[f];
    }
  }
  float al = 0.f;
#pragma unroll
  for (int c = 0; c < 16; ++c) {
    hs[(size_t)n * 16 + c] = __float2half(acc[c]);
    al += acc[c] * sm.n.sa[c];
  }
  als[n] = al;
  ald[n] = ad;
}

// ---------------- CSR stage 2: half-bucket sort, both graphs ----------------
__global__ void k_sort2_both(const unsigned* __restrict__ part0,
                             const unsigned* __restrict__ part1,
                             const int* __restrict__ bcnt,
                             int* __restrict__ col0, int* __restrict__ col1,
                             int* __restrict__ rp0, int* __restrict__ rp1) {
  __shared__ unsigned s_sorted[CAPH];
  __shared__ int hist[512];
  __shared__ int ps[512];
  __shared__ int cur[512];
  __shared__ int s_tot;
  int bb = blockIdx.x;
  const unsigned* part; const int* bc; int* col; int* rp;
  int hsh, hmask, ns, sdiv;
  if (bb < NHALF) { part = part0; bc = bcnt; col = col0; rp = rp0;
                    hsh = 7; hmask = 127; ns = 4; sdiv = SHARD_DIV; }
  else { bb -= NHALF; part = part1; bc = bcnt + 256; col = col1; rp = rp1;
         hsh = 9; hmask = 511; ns = 1; sdiv = 1 << 30; }
  int t = threadIdx.x;
  int f = bb >> 1;
  int half = bb & 1;
  int cnt = min(bc[f], CAPC);
  int cnt4 = cnt & ~3;
  int slot = bb * CAPH;
  const unsigned* pp = part + (size_t)f * CAPC;
  hist[t] = 0;
  __syncthreads();
  for (int i = t * 4; i + 3 < cnt; i += 2048) {
    uint4 e4 = *(const uint4*)(pp + i);
    unsigned ee[4] = {e4.x, e4.y, e4.z, e4.w};
#pragma unroll
    for (int q = 0; q < 4; ++q) {
      int dl = (int)(ee[q] >> 18);
      if ((dl >> hsh) == half) {
        int sv = (int)(ee[q] & 0x3FFFFu);
        int bin = (ns == 4) ? ((dl & hmask) << 2) + sv / sdiv : (dl & hmask);
        atomicAdd(&hist[bin], 1);
      }
    }
  }
  for (int i = cnt4 + t; i < cnt; i += 512) {
    unsigned e = pp[i];
    int dl = (int)(e >> 18);
    if ((dl >> hsh) == half) {
      int sv = (int)(e & 0x3FFFFu);
      int bin = (ns == 4) ? ((dl & hmask) << 2) + sv / sdiv : (dl & hmask);
      atomicAdd(&hist[bin], 1);
    }
  }
  __syncthreads();
  int v = hist[t];
  ps[t] = v;
  __syncthreads();
  for (int off = 1; off < 512; off <<= 1) {
    int u = (t >= off) ? ps[t - off] : 0;
    __syncthreads();
    ps[t] += u;
    __syncthreads();
  }
  int excl = ps[t] - v;
  rp[bb * 513 + t] = slot + excl;
  if (t == 511) {
    int tot = min(ps[511], CAPH);
    rp[bb * 513 + 512] = slot + tot;
    s_tot = tot;
  }
  cur[t] = excl;
  __syncthreads();
  for (int i = t * 4; i + 3 < cnt; i += 2048) {
    uint4 e4 = *(const uint4*)(pp + i);
    unsigned ee[4] = {e4.x, e4.y, e4.z, e4.w};
#pragma unroll
    for (int q = 0; q < 4; ++q) {
      int dl = (int)(ee[q] >> 18);
      if ((dl >> hsh) == half) {
        int sv = (int)(ee[q] & 0x3FFFFu);
        int bin = (ns == 4) ? ((dl & hmask) << 2) + sv / sdiv : (dl & hmask);
        int r = atomicAdd(&cur[bin], 1);
        if (r < CAPH) s_sorted[r] = (unsigned)sv;
      }
    }
  }
  for (int i = cnt4 + t; i < cnt; i += 512) {
    unsigned e = pp[i];
    int dl = (int)(e >> 18);
    if ((dl >> hsh) == half) {
      int sv = (int)(e & 0x3FFFFu);
      int bin = (ns == 4) ? ((dl & hmask) << 2) + sv / sdiv : (dl & hmask);
      int r = atomicAdd(&cur[bin], 1);
      if (r < CAPH) s_sorted[r] = (unsigned)sv;
    }
  }
  __syncthreads();
  int tot = s_tot;
  for (int i = t; i < tot; i += 512) col[slot + i] = (int)s_sorted[i];
}

// ---------------- mega layer-1 gather (8-lane paired groups) ----------------
// Each edge owned by a lane PAIR: lane h loads 16B half of the 32B hs row in
// one instruction (same 64B line as partner -> TA merges to 1 line request).
// alpha = dot(hs_row, a1_s) computed in-register (partial 8-dot + pair
// shfl_xor) -> no as[] gather at all. 2-stage pipeline on col+payload.
__device__ __forceinline__ void gat_pair8(
    const int* __restrict__ col, const __half* __restrict__ hs,
    int beg, int end, int j, float adv, const float (&sa)[8],
    float (&acc)[8], float& se) {
  int h = j & 1;
  int k0 = beg + (j >> 1);
  if (k0 >= end) return;
  int sv0 = col[k0];
  int k1 = k0 + 4;
  int sv1 = (k1 < end) ? col[k1] : -1;
  uint4 hv0 = *(const uint4*)(hs + (size_t)sv0 * 16 + h * 8);
  for (;;) {
    // issue next edge's payload + col for i+2
    uint4 hv1 = hv0;
    int sv2 = -1;
    int k2 = k1 + 4;
    if (sv1 >= 0) {
      hv1 = *(const uint4*)(hs + (size_t)sv1 * 16 + h * 8);
      sv2 = (k2 < end) ? col[k2] : -1;
    }
    // consume current edge
    union { uint4 v; __half hh[8]; } b;
    b.v = hv0;
    float f[8];
    float p = 0.f;
#pragma unroll
    for (int cc = 0; cc < 8; ++cc) {
      f[cc] = __half2float(b.hh[cc]);
      p += f[cc] * sa[cc];
    }
    float afull = p + __shfl_xor(p, 1, 8);
    float w = __expf(lrelu(afull + adv));
    se += w;
#pragma unroll
    for (int cc = 0; cc < 8; ++cc) acc[cc] += w * f[cc];
    if (sv1 < 0) break;
    hv0 = hv1;
    sv1 = sv2;
    k1 = k2;
  }
}

__global__ void k_megaL1(
    const int* __restrict__ rp_ub, const int* __restrict__ col_ub,
    const float* __restrict__ a1s_ub, const float* __restrict__ ad_b,
    const __half* __restrict__ hs_u,
    float* __restrict__ acc_sl, float* __restrict__ se_sl,
    const int* __restrict__ rp_bu, const int* __restrict__ col_bu,
    const float* __restrict__ a1s_bu, const float* __restrict__ ad_u,
    const __half* __restrict__ hs_b,
    const float* __restrict__ b1bu,
    const float* __restrict__ W2ub_s, const float* __restrict__ a2ub_s,
    const float* __restrict__ W2bu_d, const float* __restrict__ a2bu_d,
    float4* __restrict__ pk_u, int NB, int NU, int ubBlocks) {
  __shared__ float sW2[32], sa2[2], sv2[16], sb1[16], sAub[16], sAbu[16];
  int t = threadIdx.x;
  if (t < 32) sW2[t] = W2ub_s[t];
  if (t < 2) sa2[t] = a2ub_s[t];
  if (t < 16) {
    float s = 0.f;
    for (int cc = 0; cc < 2; ++cc) s += W2bu_d[t * 2 + cc] * a2bu_d[cc];
    sv2[t] = s;
    sb1[t] = b1bu[t];
    sAub[t] = a1s_ub[t];
    sAbu[t] = a1s_bu[t];
  }
  __syncthreads();
  int b = blockIdx.x;
  int j = t & 7;
  int h = j & 1;
  if (b < ubBlocks) {
    // 32 badges per block, one shard per block, xcd-pinned
    int xcd = b & 7;
    int s = xcd >> 1;
    int sub = ((b >> 3) << 1) | (xcd & 1);
    int n = sub * 32 + (t >> 3);
    if (n >= NB) return;
    int base = (n >> 7) * 513 + (n & 127) * 4 + s;
    int beg = rp_ub[base], end = rp_ub[base + 1];
    float adv = ad_b[n];
    float sa[8];
#pragma unroll
    for (int cc = 0; cc < 8; ++cc) sa[cc] = sAub[h * 8 + cc];
    float acc[8];
#pragma unroll
    for (int cc = 0; cc < 8; ++cc) acc[cc] = 0.f;
    float se = 0.f;
    gat_pair8(col_ub, hs_u, beg, end, j, adv, sa, acc, se);
#pragma unroll
    for (int m = 2; m < 8; m <<= 1) {
      se += __shfl_xor(se, m, 8);
#pragma unroll
      for (int cc = 0; cc < 8; ++cc) acc[cc] += __shfl_xor(acc[cc], m, 8);
    }
    if (j < 2) {
      float* o = acc_sl + ((size_t)s * NB + n) * 16 + h * 8;
#pragma unroll
      for (int cc = 0; cc < 8; ++cc) o[cc] = acc[cc];
      if (j == 0) se_sl[s * NB + n] = se;
    }
  } else {
    int n = (b - ubBlocks) * 32 + (t >> 3);
    if (n >= NU) return;
    int base = (n >> 9) * 513 + (n & 511);
    int beg = rp_bu[base], end = rp_bu[base + 1];
    float adv = ad_u[n];
    float sa[8];
#pragma unroll
    for (int cc = 0; cc < 8; ++cc) sa[cc] = sAbu[h * 8 + cc];
    float acc[8];
#pragma unroll
    for (int cc = 0; cc < 8; ++cc) acc[cc] = 0.f;
    float se = 0.f;
    gat_pair8(col_bu, hs_b, beg, end, j, adv, sa, acc, se);
#pragma unroll
    for (int m = 2; m < 8; m <<= 1) {
      se += __shfl_xor(se, m, 8);
#pragma unroll
      for (int cc = 0; cc < 8; ++cc) acc[cc] += __shfl_xor(acc[cc], m, 8);
    }
    // inline L2 user transform: each half computes partials over its 8 chans
    float inv = 1.f / (se + 1e-16f);
    float ph0 = 0.f, ph1 = 0.f, padv = 0.f;
#pragma unroll
    for (int cc = 0; cc < 8; ++cc) {
      int c = h * 8 + cc;
      float xv = fmaxf(acc[cc] * inv + sb1[c], 0.f);
      ph0 += xv * sW2[c * 2];
      ph1 += xv * sW2[c * 2 + 1];
      padv += xv * sv2[c];
    }
    ph0 += __shfl_xor(ph0, 1, 8);
    ph1 += __shfl_xor(ph1, 1, 8);
    padv += __shfl_xor(padv, 1, 8);
    if (j == 0)
      pk_u[n] = make_float4(ph0 * sa2[0] + ph1 * sa2[1], ph0, ph1, padv);
  }
}

// ---------------- finalize badges + inline layer-2 badge transform ----------------
__global__ void k_finL1b(
    const float* __restrict__ acc_sl, const float* __restrict__ se_sl,
    const float* __restrict__ b1ub,
    const float* __restrict__ W2bu_s, const float* __restrict__ a2bu_s,
    const float* __restrict__ W2ub_d, const float* __restrict__ a2ub_d,
    float4* __restrict__ pk_b, int NB) {
  __shared__ float sW2[32], sa2[2], sv2[16], sb1[16];
  int t = threadIdx.x;
  if (t < 32) sW2[t] = W2bu_s[t];
  if (t < 2) sa2[t] = a2bu_s[t];
  if (t < 16) {
    float s = 0.f;
    for (int cc = 0; cc < 2; ++cc) s += W2ub_d[t * 2 + cc] * a2ub_d[cc];
    sv2[t] = s;
    sb1[t] = b1ub[t];
  }
  __syncthreads();
  int n = blockIdx.x * 256 + t;
  if (n >= NB) return;
  float a[16];
#pragma unroll
  for (int c = 0; c < 16; ++c) a[c] = 0.f;
  float se = 0.f;
  for (int s = 0; s < 4; ++s) {
    const float4* p = (const float4*)(acc_sl + ((size_t)s * NB + n) * 16);
    float4 v0 = p[0], v1 = p[1], v2 = p[2], v3 = p[3];
    a[0] += v0.x; a[1] += v0.y; a[2] += v0.z; a[3] += v0.w;
    a[4] += v1.x; a[5] += v1.y; a[6] += v1.z; a[7] += v1.w;
    a[8] += v2.x; a[9] += v2.y; a[10] += v2.z; a[11] += v2.w;
    a[12] += v3.x; a[13] += v3.y; a[14] += v3.z; a[15] += v3.w;
    se += se_sl[s * NB + n];
  }
  float inv = 1.f / (se + 1e-16f);
  float h0 = 0.f, h1 = 0.f, advn = 0.f;
#pragma unroll
  for (int c = 0; c < 16; ++c) {
    float xv = fmaxf(a[c] * inv + sb1[c], 0.f);
    h0 += xv * sW2[c * 2];
    h1 += xv * sW2[c * 2 + 1];
    advn += xv * sv2[c];
  }
  pk_b[n] = make_float4(h0 * sa2[0] + h1 * sa2[1], h0, h1, advn);
}

// ---------------- fused layer-2 output gathers (packed tables, 4-lane groups, 2-stage pipeline) ----------------
__global__ void k_gatherL2(
    const int* __restrict__ rp0, const int* __restrict__ col0,
    const int* __restrict__ rp1, const int* __restrict__ col1,
    const float4* __restrict__ pk_u, const float4* __restrict__ pk_b,
    const float* __restrict__ b2ub, const float* __restrict__ b2bu,
    float* __restrict__ ob, float* __restrict__ ou,
    int NB, int NU, int g0) {
  int blk = blockIdx.x;
  const int *rp, *col; const float4 *pksrc, *pkown; const float* bb; float* out;
  int N, lsh, nsg;
  if (blk < g0) { rp = rp0; col = col0; pksrc = pk_u; pkown = pk_b; bb = b2ub;
                  out = ob; N = NB; lsh = 7; nsg = 4; }
  else { blk -= g0; rp = rp1; col = col1; pksrc = pk_b; pkown = pk_u; bb = b2bu;
         out = ou; N = NU; lsh = 9; nsg = 1; }
  int n = blk * 64 + (threadIdx.x >> 2);
  int j = threadIdx.x & 3;
  if (n >= N) return;
  int base = (n >> lsh) * 513 + (n & ((1 << lsh) - 1)) * nsg;
  int beg = rp[base], end = rp[base + nsg];
  float adv = pkown[n].w;
  float a0 = 0.f, a1 = 0.f, se = 0.f;
  // stride-4 coalesced, 2-stage pipeline (payload for i+1 issued before
  // consuming i; col prefetched for i+2)
  int k0 = beg + j;
  if (k0 < end) {
    int c0 = col[k0];
    int k1 = k0 + 4;
    int c1 = (k1 < end) ? col[k1] : -1;
    float4 p0 = pksrc[c0];
    for (;;) {
      float4 p1 = p0;
      int c2 = -1;
      int k2 = k1 + 4;
      if (c1 >= 0) {
        p1 = pksrc[c1];
        c2 = (k2 < end) ? col[k2] : -1;
      }
      float w = __expf(lrelu(p0.x + adv));
      se += w;
      a0 += w * p0.y;
      a1 += w * p0.z;
      if (c1 < 0) break;
      p0 = p1;
      c1 = c2;
      k1 = k2;
    }
  }
#pragma unroll
  for (int m = 1; m < 4; m <<= 1) {
    se += __shfl_xor(se, m, 4);
    a0 += __shfl_xor(a0, m, 4);
    a1 += __shfl_xor(a1, m, 4);
  }
  if (j == 0) {
    float inv = 1.f / (se + 1e-16f);
    out[(size_t)n * 2] = a0 * inv + bb[0];
    out[(size_t)n * 2 + 1] = a1 * inv + bb[1];
  }
}

extern "C" void kernel_launch(void* const* d_in, const int* in_sizes, int n_in,
                              void* d_out, int out_size, void* d_ws, size_t ws_size,
                              hipStream_t stream) {
  const int NU = 200000, NB = 50000;
  const float* x_user  = (const float*)d_in[0];
  const float* x_badge = (const float*)d_in[1];
  const int* ub_src = (const int*)d_in[2];
  const int* ub_dst = (const int*)d_in[3];
  const int* bu_src = (const int*)d_in[4];
  const int* bu_dst = (const int*)d_in[5];
  const int nE = in_sizes[2];

  const float* W1_ub_s = (const float*)d_in[8];
  const float* W1_ub_d = (const float*)d_in[9];
  const float* a1_ub_s = (const float*)d_in[10];
  const float* a1_ub_d = (const float*)d_in[11];
  const float* b1_ub   = (const float*)d_in[12];
  const float* W2_ub_s = (const float*)d_in[13];
  const float* W2_ub_d = (const float*)d_in[14];
  const float* a2_ub_s = (const float*)d_in[15];
  const float* a2_ub_d = (const float*)d_in[16];
  const float* b2_ub   = (const float*)d_in[17];
  const float* W1_bu_s = (const float*)d_in[18];
  const float* W1_bu_d = (const float*)d_in[19];
  const float* a1_bu_s = (const float*)d_in[20];
  const float* a1_bu_d = (const float*)d_in[21];
  const float* b1_bu   = (const float*)d_in[22];
  const float* W2_bu_s = (const float*)d_in[23];
  const float* W2_bu_d = (const float*)d_in[24];
  const float* a2_bu_s = (const float*)d_in[25];
  const float* a2_bu_d = (const float*)d_in[26];
  const float* b2_bu   = (const float*)d_in[27];

  const int pblocks = (nE + PART_PER - 1) / PART_PER;
  const int gNU = (NU + 255) / 256;        // 782
  const int gNB = (NB + 255) / 256;        // 196

  // ---- workspace carve-up ----
  char* wsb = (char*)d_ws;
  size_t off = 0;
  auto ialloc = [&](size_t n) { int* p = (int*)(wsb + off); off += n * 4; return p; };
  int* rp2_ub = ialloc((size_t)NHALF * 513);
  int* rp2_bu = ialloc((size_t)NHALF * 513);
  int* bcnt   = ialloc(512);
  int* col_ub = ialloc((size_t)NHALF * CAPH);
  int* col_bu = ialloc((size_t)NHALF * CAPH);
  off = (off + 15) & ~(size_t)15;
  const size_t partBytes = (size_t)2 * NBC * CAPC * 4;
  const size_t nodeBytes = (size_t)NU * 32 + (size_t)NB * 32 +
                           (size_t)(NU + NB) * 8 + 1024;
  bool fused = ws_size >= off + partBytes + nodeBytes + 4096;
  char* partBase = wsb + off;
  char* nodeBase = fused ? (partBase + partBytes) : partBase;
  unsigned* part0 = (unsigned*)partBase;
  unsigned* part1 = part0 + (size_t)NBC * CAPC;
  size_t poff = 0;
  auto falloc = [&](size_t n) { float* p = (float*)(nodeBase + poff); poff += n * 4; return p; };
  auto halloc = [&](size_t n) { __half* p = (__half*)(nodeBase + poff); poff += n * 2; return p; };
  __half* hs_u1 = halloc((size_t)NU * 16);
  __half* hs_b1 = halloc((size_t)NB * 16);
  float* as_u1  = falloc(NU);
  float* ad_u1  = falloc(NU);
  float* as_b1  = falloc(NB);
  float* ad_b1  = falloc(NB);
  poff = (poff + 15) & ~(size_t)15;
  float4* pk_u  = (float4*)(nodeBase + poff); poff += (size_t)NU * 16;
  float4* pk_b  = (float4*)(nodeBase + poff); poff += (size_t)NB * 16;
  char* accBase = fused ? partBase : (nodeBase + ((poff + 15) & ~(size_t)15));
  float* acc_sl = (float*)accBase;
  float* se_sl  = (float*)(accBase + (size_t)4 * NB * 16 * 4);

  float* ou = (float*)d_out;                   // [NU,2]
  float* ob = (float*)d_out + (size_t)NU * 2;  // [NB,2]

  // megaL1: 8-lane paired groups -> 32 nodes per 256-thread block
  const int chunksB = (NB + 31) / 32;                 // 1563
  const int ubBlocks = ((chunksB + 1) / 2) * 8;       // 6256 (xcd-pinned pairs)
  const int buBlocks = (NU + 31) / 32;                // 6250
  // gatherL2: 4-lane groups -> 64 nodes per block
  const int g0 = (NB + 63) / 64;                      // 782
  const int g1 = (NU + 63) / 64;                      // 3125

  hipMemsetAsync(bcnt, 0, 512 * 4, stream);
  if (fused) {
    k_stageA<<<dim3(2 * pblocks + gNU + gNB), dim3(256), 0, stream>>>(
        ub_src, ub_dst, bu_src, bu_dst, nE, pblocks, part0, part1, bcnt,
        x_user, x_badge, W1_ub_s, a1_ub_s, W1_bu_d, a1_bu_d,
        W1_bu_s, a1_bu_s, W1_ub_d, a1_ub_d,
        hs_u1, as_u1, ad_u1, hs_b1, as_b1, ad_b1, NU, NB, gNU,
        2 * pblocks, gNU + gNB);
    k_sort2_both<<<dim3(2 * NHALF), dim3(512), 0, stream>>>(
        part0, part1, bcnt, col_ub, col_bu, rp2_ub, rp2_bu);
  } else {
    k_stageA<<<dim3(2 * pblocks), dim3(256), 0, stream>>>(
        ub_src, ub_dst, bu_src, bu_dst, nE, pblocks, part0, part1, bcnt,
        x_user, x_badge, W1_ub_s, a1_ub_s, W1_bu_d, a1_bu_d,
        W1_bu_s, a1_bu_s, W1_ub_d, a1_ub_d,
        hs_u1, as_u1, ad_u1, hs_b1, as_b1, ad_b1, NU, NB, gNU,
        2 * pblocks, 0);
    k_sort2_both<<<dim3(2 * NHALF), dim3(512), 0, stream>>>(
        part0, part1, bcnt, col_ub, col_bu, rp2_ub, rp2_bu);
    k_stageA<<<dim3(gNU + gNB), dim3(256), 0, stream>>>(
        ub_src, ub_dst, bu_src, bu_dst, nE, pblocks, part0, part1, bcnt,
        x_user, x_badge, W1_ub_s, a1_ub_s, W1_bu_d, a1_bu_d,
        W1_bu_s, a1_bu_s, W1_ub_d, a1_ub_d,
        hs_u1, as_u1, ad_u1, hs_b1, as_b1, ad_b1, NU, NB, gNU,
        0, gNU + gNB);
  }
  k_megaL1<<<dim3(ubBlocks + buBlocks), dim3(256), 0, stream>>>(
      rp2_ub, col_ub, a1_ub_s, ad_b1, hs_u1, acc_sl, se_sl,
      rp2_bu, col_bu, a1_bu_s, ad_u1, hs_b1,
      b1_bu, W2_ub_s, a2_ub_s, W2_bu_d, a2_bu_d,
      pk_u, NB, NU, ubBlocks);
  k_finL1b<<<dim3(gNB), dim3(256), 0, stream>>>(
      acc_sl, se_sl, b1_ub, W2_bu_s, a2_bu_s, W2_ub_d, a2_ub_d, pk_b, NB);
  k_gatherL2<<<dim3(g0 + g1), dim3(256), 0, stream>>>(
      rp2_ub, col_ub, rp2_bu, col_bu, pk_u, pk_b, b2_ub, b2_bu, ob, ou, NB, NU, g0);
}

// Round 8
// 426.047 us; speedup vs baseline: 1.0312x; 1.0312x over previous
//
#include <hip/hip_runtime.h>
#include <hip/hip_fp16.h>
#include <math.h>

// HeteroGNN: 2-layer bipartite single-head GAT (users<->badges).
// R20 (from R19 @439 REGRESSED; PART_PER 2440 raised occ 51->72% but dur
// 100->107 and WRITE_SIZE 60.6->72.5MB -> stageA is NOT latency-bound, it's
// bound by flush scatter-write granularity: run length PART_PER/196 words
// per (block,bucket); smaller runs = more partial 64B lines):
//   - PART_PER 4880 -> 9760 (follow the gradient the other way): runs ~50
//     words (200B, ~1.3x line overhead vs 1.5x), per-block scan amortizes
//     2x, blocks halve. LDS ~43KB -> 3 blocks/CU (37% occ) -- R19 proved
//     occupancy non-binding here. per = 9748 % 4 == 0 -> int4 ok.
// Everything else identical to R18 (pair-gather megaL1 w/ alpha-via-dot,
// stageA interleave, int4 edge streams, XCD-pinned shards, packed-float4
// L2 gather w/ 2-stage pipeline).

#define NEG_SLOPE 0.2f
#define PART_PER 9760
#define NBC 196
#define CAPC 27072
#define NHALF 392
#define CAPH 13824
#define SHARD_DIV 50000

__device__ __forceinline__ float lrelu(float x) { return x > 0.f ? x : NEG_SLOPE * x; }

// ---------------- stage A: coarse partition (both graphs) + L1 node transforms ----------------
__global__ void k_stageA(
    const int* __restrict__ src0, const int* __restrict__ dst0,
    const int* __restrict__ src1, const int* __restrict__ dst1,
    int nE, int pblocks, unsigned* __restrict__ part0, unsigned* __restrict__ part1,
    int* __restrict__ bcnt,
    const float* __restrict__ xu, const float* __restrict__ xb,
    const float* __restrict__ Wub_s, const float* __restrict__ aub_s,
    const float* __restrict__ Wbu_d, const float* __restrict__ abu_d,
    const float* __restrict__ Wbu_s, const float* __restrict__ abu_s,
    const float* __restrict__ Wub_d, const float* __restrict__ aub_d,
    __half* __restrict__ hs_u, float* __restrict__ as_u, float* __restrict__ ad_u,
    __half* __restrict__ hs_b, float* __restrict__ as_b, float* __restrict__ ad_b,
    int NU, int NB, int gNU, int partBlocks, int nodeBlocks) {
  union Sm {
    struct { unsigned s_sorted[PART_PER]; int h[257]; int ps[256]; int resb[256]; int cur[256]; } p;
    struct { float sW[64 * 16]; float sa[16]; float sv[64]; } n;
  };
  __shared__ Sm sm;
  int t = threadIdx.x;
  // ---- interleave mapping: 2 partition blocks : 1 node block ----
  int b = blockIdx.x;
  int k = min(nodeBlocks, partBlocks / 2);
  int inter = 3 * k;
  int partIdx = -1, nodeIdx = -1;
  if (b < inter) {
    if ((b % 3) == 2) nodeIdx = b / 3;
    else partIdx = (b / 3) * 2 + (b % 3);
  } else {
    int rem = b - inter;
    int ptail = partBlocks - 2 * k;
    if (rem < ptail) partIdx = 2 * k + rem;
    else nodeIdx = k + (rem - ptail);
  }
  if (partIdx >= 0) {
    // ===== partition branch =====
    int gb = partIdx;
    const int* src; const int* dst; unsigned* part; int* bc; int shift; int mask;
    if (gb < pblocks) { src = src0; dst = dst0; part = part0; bc = bcnt; shift = 8; mask = 255; }
    else { gb -= pblocks; src = src1; dst = dst1; part = part1; bc = bcnt + 256; shift = 10; mask = 1023; }
    int per = (nE + pblocks - 1) / pblocks;
    int beg = gb * per;
    int end = min(beg + per, nE);
    int cnt = end - beg;
    int cnt4 = cnt & ~3;
    sm.p.h[t] = 0;
    __syncthreads();
    // hist: int4 loads (beg 16B-aligned: per % 4 == 0)
    for (int i = beg + t * 4; i + 3 < end; i += 1024) {
      int4 d4 = *(const int4*)(dst + i);
      atomicAdd(&sm.p.h[d4.x >> shift], 1);
      atomicAdd(&sm.p.h[d4.y >> shift], 1);
      atomicAdd(&sm.p.h[d4.z >> shift], 1);
      atomicAdd(&sm.p.h[d4.w >> shift], 1);
    }
    for (int i = beg + cnt4 + t; i < end; i += 256) atomicAdd(&sm.p.h[dst[i] >> shift], 1);
    __syncthreads();
    int v = sm.p.h[t];
    sm.p.ps[t] = v;
    __syncthreads();
    for (int off = 1; off < 256; off <<= 1) {
      int u = (t >= off) ? sm.p.ps[t - off] : 0;
      __syncthreads();
      sm.p.ps[t] += u;
      __syncthreads();
    }
    int excl = sm.p.ps[t] - v;
    sm.p.resb[t] = (t < NBC && v > 0) ? atomicAdd(&bc[t], v) : 0;
    __syncthreads();
    sm.p.h[t] = excl;
    sm.p.cur[t] = excl;
    if (t == 255) sm.p.h[256] = excl + v;
    __syncthreads();
    // scatter: int4 loads of dst+src
    for (int i = beg + t * 4; i + 3 < end; i += 1024) {
      int4 d4 = *(const int4*)(dst + i);
      int4 s4 = *(const int4*)(src + i);
      int r;
      r = atomicAdd(&sm.p.cur[d4.x >> shift], 1);
      sm.p.s_sorted[r] = ((unsigned)(d4.x & mask) << 18) | (unsigned)s4.x;
      r = atomicAdd(&sm.p.cur[d4.y >> shift], 1);
      sm.p.s_sorted[r] = ((unsigned)(d4.y & mask) << 18) | (unsigned)s4.y;
      r = atomicAdd(&sm.p.cur[d4.z >> shift], 1);
      sm.p.s_sorted[r] = ((unsigned)(d4.z & mask) << 18) | (unsigned)s4.z;
      r = atomicAdd(&sm.p.cur[d4.w >> shift], 1);
      sm.p.s_sorted[r] = ((unsigned)(d4.w & mask) << 18) | (unsigned)s4.w;
    }
    for (int i = beg + cnt4 + t; i < end; i += 256) {
      int d = dst[i];
      int r = atomicAdd(&sm.p.cur[d >> shift], 1);
      sm.p.s_sorted[r] = ((unsigned)(d & mask) << 18) | (unsigned)src[i];
    }
    __syncthreads();
    // flush: 4 concurrent binary-search chains per thread (ILP)
    for (int i = t; i < cnt; i += 1024) {
      int i1 = i + 256, i2 = i + 512, i3 = i + 768;
      int lo0 = 0, lo1 = 0, lo2 = 0, lo3 = 0;
      int hi0 = 256, hi1 = 256, hi2 = 256, hi3 = 256;
#pragma unroll
      for (int s = 0; s < 8; ++s) {
        int m0 = (lo0 + hi0) >> 1; if (sm.p.h[m0] <= i)  lo0 = m0; else hi0 = m0;
        int m1 = (lo1 + hi1) >> 1; if (sm.p.h[m1] <= i1) lo1 = m1; else hi1 = m1;
        int m2 = (lo2 + hi2) >> 1; if (sm.p.h[m2] <= i2) lo2 = m2; else hi2 = m2;
        int m3 = (lo3 + hi3) >> 1; if (sm.p.h[m3] <= i3) lo3 = m3; else hi3 = m3;
      }
      { int p = sm.p.resb[lo0] + (i - sm.p.h[lo0]);
        if (p < CAPC) part[(size_t)lo0 * CAPC + p] = sm.p.s_sorted[i]; }
      if (i1 < cnt) { int p = sm.p.resb[lo1] + (i1 - sm.p.h[lo1]);
        if (p < CAPC) part[(size_t)lo1 * CAPC + p] = sm.p.s_sorted[i1]; }
      if (i2 < cnt) { int p = sm.p.resb[lo2] + (i2 - sm.p.h[lo2]);
        if (p < CAPC) part[(size_t)lo2 * CAPC + p] = sm.p.s_sorted[i2]; }
      if (i3 < cnt) { int p = sm.p.resb[lo3] + (i3 - sm.p.h[lo3]);
        if (p < CAPC) part[(size_t)lo3 * CAPC + p] = sm.p.s_sorted[i3]; }
    }
    return;
  }
  // ===== nodes branch =====
  int blk = nodeIdx;
  bool us = blk < gNU;
  const float* x  = us ? xu : xb;
  const float* Ws = us ? Wub_s : Wbu_s;
  const float* As = us ? aub_s : abu_s;
  const float* Wd = us ? Wbu_d : Wub_d;
  const float* Ad = us ? abu_d : aub_d;
  __half* hs = us ? hs_u : hs_b;
  float* als = us ? as_u : as_b;
  float* ald = us ? ad_u : ad_b;
  int N = us ? NU : NB;
  for (int i = t; i < 64 * 16; i += 256) sm.n.sW[i] = Ws[i];
  if (t < 16) sm.n.sa[t] = As[t];
  if (t < 64) {
    float s = 0.f;
    for (int c = 0; c < 16; ++c) s += Wd[t * 16 + c] * Ad[c];
    sm.n.sv[t] = s;
  }
  __syncthreads();
  int n = (us ? blk : blk - gNU) * 256 + t;
  if (n >= N) return;
  float acc[16];
#pragma unroll
  for (int c = 0; c < 16; ++c) acc[c] = 0.f;
  float ad = 0.f;
  const float4* xr4 = (const float4*)(x + (size_t)n * 64);
#pragma unroll 4
  for (int f4 = 0; f4 < 16; ++f4) {
    float4 xv4 = xr4[f4];
    float xv[4] = {xv4.x, xv4.y, xv4.z, xv4.w};
#pragma unroll
    for (int q = 0; q < 4; ++q) {
      int f = f4 * 4 + q;
#pragma unroll
      for (int c = 0; c < 16; ++c) acc[c] += xv[q] * sm.n.sW[f * 16 + c];
      ad += xv[q] * sm.n.sv[f];
    }
  }
  float al = 0.f;
#pragma unroll
  for (int c = 0; c < 16; ++c) {
    hs[(size_t)n * 16 + c] = __float2half(acc[c]);
    al += acc[c] * sm.n.sa[c];
  }
  als[n] = al;
  ald[n] = ad;
}

// ---------------- CSR stage 2: half-bucket sort, both graphs ----------------
__global__ void k_sort2_both(const unsigned* __restrict__ part0,
                             const unsigned* __restrict__ part1,
                             const int* __restrict__ bcnt,
                             int* __restrict__ col0, int* __restrict__ col1,
                             int* __restrict__ rp0, int* __restrict__ rp1) {
  __shared__ unsigned s_sorted[CAPH];
  __shared__ int hist[512];
  __shared__ int ps[512];
  __shared__ int cur[512];
  __shared__ int s_tot;
  int bb = blockIdx.x;
  const unsigned* part; const int* bc; int* col; int* rp;
  int hsh, hmask, ns, sdiv;
  if (bb < NHALF) { part = part0; bc = bcnt; col = col0; rp = rp0;
                    hsh = 7; hmask = 127; ns = 4; sdiv = SHARD_DIV; }
  else { bb -= NHALF; part = part1; bc = bcnt + 256; col = col1; rp = rp1;
         hsh = 9; hmask = 511; ns = 1; sdiv = 1 << 30; }
  int t = threadIdx.x;
  int f = bb >> 1;
  int half = bb & 1;
  int cnt = min(bc[f], CAPC);
  int cnt4 = cnt & ~3;
  int slot = bb * CAPH;
  const unsigned* pp = part + (size_t)f * CAPC;
  hist[t] = 0;
  __syncthreads();
  for (int i = t * 4; i + 3 < cnt; i += 2048) {
    uint4 e4 = *(const uint4*)(pp + i);
    unsigned ee[4] = {e4.x, e4.y, e4.z, e4.w};
#pragma unroll
    for (int q = 0; q < 4; ++q) {
      int dl = (int)(ee[q] >> 18);
      if ((dl >> hsh) == half) {
        int sv = (int)(ee[q] & 0x3FFFFu);
        int bin = (ns == 4) ? ((dl & hmask) << 2) + sv / sdiv : (dl & hmask);
        atomicAdd(&hist[bin], 1);
      }
    }
  }
  for (int i = cnt4 + t; i < cnt; i += 512) {
    unsigned e = pp[i];
    int dl = (int)(e >> 18);
    if ((dl >> hsh) == half) {
      int sv = (int)(e & 0x3FFFFu);
      int bin = (ns == 4) ? ((dl & hmask) << 2) + sv / sdiv : (dl & hmask);
      atomicAdd(&hist[bin], 1);
    }
  }
  __syncthreads();
  int v = hist[t];
  ps[t] = v;
  __syncthreads();
  for (int off = 1; off < 512; off <<= 1) {
    int u = (t >= off) ? ps[t - off] : 0;
    __syncthreads();
    ps[t] += u;
    __syncthreads();
  }
  int excl = ps[t] - v;
  rp[bb * 513 + t] = slot + excl;
  if (t == 511) {
    int tot = min(ps[511], CAPH);
    rp[bb * 513 + 512] = slot + tot;
    s_tot = tot;
  }
  cur[t] = excl;
  __syncthreads();
  for (int i = t * 4; i + 3 < cnt; i += 2048) {
    uint4 e4 = *(const uint4*)(pp + i);
    unsigned ee[4] = {e4.x, e4.y, e4.z, e4.w};
#pragma unroll
    for (int q = 0; q < 4; ++q) {
      int dl = (int)(ee[q] >> 18);
      if ((dl >> hsh) == half) {
        int sv = (int)(ee[q] & 0x3FFFFu);
        int bin = (ns == 4) ? ((dl & hmask) << 2) + sv / sdiv : (dl & hmask);
        int r = atomicAdd(&cur[bin], 1);
        if (r < CAPH) s_sorted[r] = (unsigned)sv;
      }
    }
  }
  for (int i = cnt4 + t; i < cnt; i += 512) {
    unsigned e = pp[i];
    int dl = (int)(e >> 18);
    if ((dl >> hsh) == half) {
      int sv = (int)(e & 0x3FFFFu);
      int bin = (ns == 4) ? ((dl & hmask) << 2) + sv / sdiv : (dl & hmask);
      int r = atomicAdd(&cur[bin], 1);
      if (r < CAPH) s_sorted[r] = (unsigned)sv;
    }
  }
  __syncthreads();
  int tot = s_tot;
  for (int i = t; i < tot; i += 512) col[slot + i] = (int)s_sorted[i];
}

// ---------------- mega layer-1 gather (8-lane paired groups) ----------------
// Each edge owned by a lane PAIR: lane h loads 16B half of the 32B hs row in
// one instruction (same 64B line as partner -> TA merges to 1 line request).
// alpha = dot(hs_row, a1_s) computed in-register (partial 8-dot + pair
// shfl_xor) -> no as[] gather at all. 2-stage pipeline on col+payload.
__device__ __forceinline__ void gat_pair8(
    const int* __restrict__ col, const __half* __restrict__ hs,
    int beg, int end, int j, float adv, const float (&sa)[8],
    float (&acc)[8], float& se) {
  int h = j & 1;
  int k0 = beg + (j >> 1);
  if (k0 >= end) return;
  int sv0 = col[k0];
  int k1 = k0 + 4;
  int sv1 = (k1 < end) ? col[k1] : -1;
  uint4 hv0 = *(const uint4*)(hs + (size_t)sv0 * 16 + h * 8);
  for (;;) {
    // issue next edge's payload + col for i+2
    uint4 hv1 = hv0;
    int sv2 = -1;
    int k2 = k1 + 4;
    if (sv1 >= 0) {
      hv1 = *(const uint4*)(hs + (size_t)sv1 * 16 + h * 8);
      sv2 = (k2 < end) ? col[k2] : -1;
    }
    // consume current edge
    union { uint4 v; __half hh[8]; } b;
    b.v = hv0;
    float f[8];
    float p = 0.f;
#pragma unroll
    for (int cc = 0; cc < 8; ++cc) {
      f[cc] = __half2float(b.hh[cc]);
      p += f[cc] * sa[cc];
    }
    float afull = p + __shfl_xor(p, 1, 8);
    float w = __expf(lrelu(afull + adv));
    se += w;
#pragma unroll
    for (int cc = 0; cc < 8; ++cc) acc[cc] += w * f[cc];
    if (sv1 < 0) break;
    hv0 = hv1;
    sv1 = sv2;
    k1 = k2;
  }
}

__global__ void k_megaL1(
    const int* __restrict__ rp_ub, const int* __restrict__ col_ub,
    const float* __restrict__ a1s_ub, const float* __restrict__ ad_b,
    const __half* __restrict__ hs_u,
    float* __restrict__ acc_sl, float* __restrict__ se_sl,
    const int* __restrict__ rp_bu, const int* __restrict__ col_bu,
    const float* __restrict__ a1s_bu, const float* __restrict__ ad_u,
    const __half* __restrict__ hs_b,
    const float* __restrict__ b1bu,
    const float* __restrict__ W2ub_s, const float* __restrict__ a2ub_s,
    const float* __restrict__ W2bu_d, const float* __restrict__ a2bu_d,
    float4* __restrict__ pk_u, int NB, int NU, int ubBlocks) {
  __shared__ float sW2[32], sa2[2], sv2[16], sb1[16], sAub[16], sAbu[16];
  int t = threadIdx.x;
  if (t < 32) sW2[t] = W2ub_s[t];
  if (t < 2) sa2[t] = a2ub_s[t];
  if (t < 16) {
    float s = 0.f;
    for (int cc = 0; cc < 2; ++cc) s += W2bu_d[t * 2 + cc] * a2bu_d[cc];
    sv2[t] = s;
    sb1[t] = b1bu[t];
    sAub[t] = a1s_ub[t];
    sAbu[t] = a1s_bu[t];
  }
  __syncthreads();
  int b = blockIdx.x;
  int j = t & 7;
  int h = j & 1;
  if (b < ubBlocks) {
    // 32 badges per block, one shard per block, xcd-pinned
    int xcd = b & 7;
    int s = xcd >> 1;
    int sub = ((b >> 3) << 1) | (xcd & 1);
    int n = sub * 32 + (t >> 3);
    if (n >= NB) return;
    int base = (n >> 7) * 513 + (n & 127) * 4 + s;
    int beg = rp_ub[base], end = rp_ub[base + 1];
    float adv = ad_b[n];
    float sa[8];
#pragma unroll
    for (int cc = 0; cc < 8; ++cc) sa[cc] = sAub[h * 8 + cc];
    float acc[8];
#pragma unroll
    for (int cc = 0; cc < 8; ++cc) acc[cc] = 0.f;
    float se = 0.f;
    gat_pair8(col_ub, hs_u, beg, end, j, adv, sa, acc, se);
#pragma unroll
    for (int m = 2; m < 8; m <<= 1) {
      se += __shfl_xor(se, m, 8);
#pragma unroll
      for (int cc = 0; cc < 8; ++cc) acc[cc] += __shfl_xor(acc[cc], m, 8);
    }
    if (j < 2) {
      float* o = acc_sl + ((size_t)s * NB + n) * 16 + h * 8;
#pragma unroll
      for (int cc = 0; cc < 8; ++cc) o[cc] = acc[cc];
      if (j == 0) se_sl[s * NB + n] = se;
    }
  } else {
    int n = (b - ubBlocks) * 32 + (t >> 3);
    if (n >= NU) return;
    int base = (n >> 9) * 513 + (n & 511);
    int beg = rp_bu[base], end = rp_bu[base + 1];
    float adv = ad_u[n];
    float sa[8];
#pragma unroll
    for (int cc = 0; cc < 8; ++cc) sa[cc] = sAbu[h * 8 + cc];
    float acc[8];
#pragma unroll
    for (int cc = 0; cc < 8; ++cc) acc[cc] = 0.f;
    float se = 0.f;
    gat_pair8(col_bu, hs_b, beg, end, j, adv, sa, acc, se);
#pragma unroll
    for (int m = 2; m < 8; m <<= 1) {
      se += __shfl_xor(se, m, 8);
#pragma unroll
      for (int cc = 0; cc < 8; ++cc) acc[cc] += __shfl_xor(acc[cc], m, 8);
    }
    // inline L2 user transform: each half computes partials over its 8 chans
    float inv = 1.f / (se + 1e-16f);
    float ph0 = 0.f, ph1 = 0.f, padv = 0.f;
#pragma unroll
    for (int cc = 0; cc < 8; ++cc) {
      int c = h * 8 + cc;
      float xv = fmaxf(acc[cc] * inv + sb1[c], 0.f);
      ph0 += xv * sW2[c * 2];
      ph1 += xv * sW2[c * 2 + 1];
      padv += xv * sv2[c];
    }
    ph0 += __shfl_xor(ph0, 1, 8);
    ph1 += __shfl_xor(ph1, 1, 8);
    padv += __shfl_xor(padv, 1, 8);
    if (j == 0)
      pk_u[n] = make_float4(ph0 * sa2[0] + ph1 * sa2[1], ph0, ph1, padv);
  }
}

// ---------------- finalize badges + inline layer-2 badge transform ----------------
__global__ void k_finL1b(
    const float* __restrict__ acc_sl, const float* __restrict__ se_sl,
    const float* __restrict__ b1ub,
    const float* __restrict__ W2bu_s, const float* __restrict__ a2bu_s,
    const float* __restrict__ W2ub_d, const float* __restrict__ a2ub_d,
    float4* __restrict__ pk_b, int NB) {
  __shared__ float sW2[32], sa2[2], sv2[16], sb1[16];
  int t = threadIdx.x;
  if (t < 32) sW2[t] = W2bu_s[t];
  if (t < 2) sa2[t] = a2bu_s[t];
  if (t < 16) {
    float s = 0.f;
    for (int cc = 0; cc < 2; ++cc) s += W2ub_d[t * 2 + cc] * a2ub_d[cc];
    sv2[t] = s;
    sb1[t] = b1ub[t];
  }
  __syncthreads();
  int n = blockIdx.x * 256 + t;
  if (n >= NB) return;
  float a[16];
#pragma unroll
  for (int c = 0; c < 16; ++c) a[c] = 0.f;
  float se = 0.f;
  for (int s = 0; s < 4; ++s) {
    const float4* p = (const float4*)(acc_sl + ((size_t)s * NB + n) * 16);
    float4 v0 = p[0], v1 = p[1], v2 = p[2], v3 = p[3];
    a[0] += v0.x; a[1] += v0.y; a[2] += v0.z; a[3] += v0.w;
    a[4] += v1.x; a[5] += v1.y; a[6] += v1.z; a[7] += v1.w;
    a[8] += v2.x; a[9] += v2.y; a[10] += v2.z; a[11] += v2.w;
    a[12] += v3.x; a[13] += v3.y; a[14] += v3.z; a[15] += v3.w;
    se += se_sl[s * NB + n];
  }
  float inv = 1.f / (se + 1e-16f);
  float h0 = 0.f, h1 = 0.f, advn = 0.f;
#pragma unroll
  for (int c = 0; c < 16; ++c) {
    float xv = fmaxf(a[c] * inv + sb1[c], 0.f);
    h0 += xv * sW2[c * 2];
    h1 += xv * sW2[c * 2 + 1];
    advn += xv * sv2[c];
  }
  pk_b[n] = make_float4(h0 * sa2[0] + h1 * sa2[1], h0, h1, advn);
}

// ---------------- fused layer-2 output gathers (packed tables, 4-lane groups, 2-stage pipeline) ----------------
__global__ void k_gatherL2(
    const int* __restrict__ rp0, const int* __restrict__ col0,
    const int* __restrict__ rp1, const int* __restrict__ col1,
    const float4* __restrict__ pk_u, const float4* __restrict__ pk_b,
    const float* __restrict__ b2ub, const float* __restrict__ b2bu,
    float* __restrict__ ob, float* __restrict__ ou,
    int NB, int NU, int g0) {
  int blk = blockIdx.x;
  const int *rp, *col; const float4 *pksrc, *pkown; const float* bb; float* out;
  int N, lsh, nsg;
  if (blk < g0) { rp = rp0; col = col0; pksrc = pk_u; pkown = pk_b; bb = b2ub;
                  out = ob; N = NB; lsh = 7; nsg = 4; }
  else { blk -= g0; rp = rp1; col = col1; pksrc = pk_b; pkown = pk_u; bb = b2bu;
         out = ou; N = NU; lsh = 9; nsg = 1; }
  int n = blk * 64 + (threadIdx.x >> 2);
  int j = threadIdx.x & 3;
  if (n >= N) return;
  int base = (n >> lsh) * 513 + (n & ((1 << lsh) - 1)) * nsg;
  int beg = rp[base], end = rp[base + nsg];
  float adv = pkown[n].w;
  float a0 = 0.f, a1 = 0.f, se = 0.f;
  // stride-4 coalesced, 2-stage pipeline (payload for i+1 issued before
  // consuming i; col prefetched for i+2)
  int k0 = beg + j;
  if (k0 < end) {
    int c0 = col[k0];
    int k1 = k0 + 4;
    int c1 = (k1 < end) ? col[k1] : -1;
    float4 p0 = pksrc[c0];
    for (;;) {
      float4 p1 = p0;
      int c2 = -1;
      int k2 = k1 + 4;
      if (c1 >= 0) {
        p1 = pksrc[c1];
        c2 = (k2 < end) ? col[k2] : -1;
      }
      float w = __expf(lrelu(p0.x + adv));
      se += w;
      a0 += w * p0.y;
      a1 += w * p0.z;
      if (c1 < 0) break;
      p0 = p1;
      c1 = c2;
      k1 = k2;
    }
  }
#pragma unroll
  for (int m = 1; m < 4; m <<= 1) {
    se += __shfl_xor(se, m, 4);
    a0 += __shfl_xor(a0, m, 4);
    a1 += __shfl_xor(a1, m, 4);
  }
  if (j == 0) {
    float inv = 1.f / (se + 1e-16f);
    out[(size_t)n * 2] = a0 * inv + bb[0];
    out[(size_t)n * 2 + 1] = a1 * inv + bb[1];
  }
}

extern "C" void kernel_launch(void* const* d_in, const int* in_sizes, int n_in,
                              void* d_out, int out_size, void* d_ws, size_t ws_size,
                              hipStream_t stream) {
  const int NU = 200000, NB = 50000;
  const float* x_user  = (const float*)d_in[0];
  const float* x_badge = (const float*)d_in[1];
  const int* ub_src = (const int*)d_in[2];
  const int* ub_dst = (const int*)d_in[3];
  const int* bu_src = (const int*)d_in[4];
  const int* bu_dst = (const int*)d_in[5];
  const int nE = in_sizes[2];

  const float* W1_ub_s = (const float*)d_in[8];
  const float* W1_ub_d = (const float*)d_in[9];
  const float* a1_ub_s = (const float*)d_in[10];
  const float* a1_ub_d = (const float*)d_in[11];
  const float* b1_ub   = (const float*)d_in[12];
  const float* W2_ub_s = (const float*)d_in[13];
  const float* W2_ub_d = (const float*)d_in[14];
  const float* a2_ub_s = (const float*)d_in[15];
  const float* a2_ub_d = (const float*)d_in[16];
  const float* b2_ub   = (const float*)d_in[17];
  const float* W1_bu_s = (const float*)d_in[18];
  const float* W1_bu_d = (const float*)d_in[19];
  const float* a1_bu_s = (const float*)d_in[20];
  const float* a1_bu_d = (const float*)d_in[21];
  const float* b1_bu   = (const float*)d_in[22];
  const float* W2_bu_s = (const float*)d_in[23];
  const float* W2_bu_d = (const float*)d_in[24];
  const float* a2_bu_s = (const float*)d_in[25];
  const float* a2_bu_d = (const float*)d_in[26];
  const float* b2_bu   = (const float*)d_in[27];

  const int pblocks = (nE + PART_PER - 1) / PART_PER;
  const int gNU = (NU + 255) / 256;        // 782
  const int gNB = (NB + 255) / 256;        // 196

  // ---- workspace carve-up ----
  char* wsb = (char*)d_ws;
  size_t off = 0;
  auto ialloc = [&](size_t n) { int* p = (int*)(wsb + off); off += n * 4; return p; };
  int* rp2_ub = ialloc((size_t)NHALF * 513);
  int* rp2_bu = ialloc((size_t)NHALF * 513);
  int* bcnt   = ialloc(512);
  int* col_ub = ialloc((size_t)NHALF * CAPH);
  int* col_bu = ialloc((size_t)NHALF * CAPH);
  off = (off + 15) & ~(size_t)15;
  const size_t partBytes = (size_t)2 * NBC * CAPC * 4;
  const size_t nodeBytes = (size_t)NU * 32 + (size_t)NB * 32 +
                           (size_t)(NU + NB) * 8 + 1024;
  bool fused = ws_size >= off + partBytes + nodeBytes + 4096;
  char* partBase = wsb + off;
  char* nodeBase = fused ? (partBase + partBytes) : partBase;
  unsigned* part0 = (unsigned*)partBase;
  unsigned* part1 = part0 + (size_t)NBC * CAPC;
  size_t poff = 0;
  auto falloc = [&](size_t n) { float* p = (float*)(nodeBase + poff); poff += n * 4; return p; };
  auto halloc = [&](size_t n) { __half* p = (__half*)(nodeBase + poff); poff += n * 2; return p; };
  __half* hs_u1 = halloc((size_t)NU * 16);
  __half* hs_b1 = halloc((size_t)NB * 16);
  float* as_u1  = falloc(NU);
  float* ad_u1  = falloc(NU);
  float* as_b1  = falloc(NB);
  float* ad_b1  = falloc(NB);
  poff = (poff + 15) & ~(size_t)15;
  float4* pk_u  = (float4*)(nodeBase + poff); poff += (size_t)NU * 16;
  float4* pk_b  = (float4*)(nodeBase + poff); poff += (size_t)NB * 16;
  char* accBase = fused ? partBase : (nodeBase + ((poff + 15) & ~(size_t)15));
  float* acc_sl = (float*)accBase;
  float* se_sl  = (float*)(accBase + (size_t)4 * NB * 16 * 4);

  float* ou = (float*)d_out;                   // [NU,2]
  float* ob = (float*)d_out + (size_t)NU * 2;  // [NB,2]

  // megaL1: 8-lane paired groups -> 32 nodes per 256-thread block
  const int chunksB = (NB + 31) / 32;                 // 1563
  const int ubBlocks = ((chunksB + 1) / 2) * 8;       // 6256 (xcd-pinned pairs)
  const int buBlocks = (NU + 31) / 32;                // 6250
  // gatherL2: 4-lane groups -> 64 nodes per block
  const int g0 = (NB + 63) / 64;                      // 782
  const int g1 = (NU + 63) / 64;                      // 3125

  hipMemsetAsync(bcnt, 0, 512 * 4, stream);
  if (fused) {
    k_stageA<<<dim3(2 * pblocks + gNU + gNB), dim3(256), 0, stream>>>(
        ub_src, ub_dst, bu_src, bu_dst, nE, pblocks, part0, part1, bcnt,
        x_user, x_badge, W1_ub_s, a1_ub_s, W1_bu_d, a1_bu_d,
        W1_bu_s, a1_bu_s, W1_ub_d, a1_ub_d,
        hs_u1, as_u1, ad_u1, hs_b1, as_b1, ad_b1, NU, NB, gNU,
        2 * pblocks, gNU + gNB);
    k_sort2_both<<<dim3(2 * NHALF), dim3(512), 0, stream>>>(
        part0, part1, bcnt, col_ub, col_bu, rp2_ub, rp2_bu);
  } else {
    k_stageA<<<dim3(2 * pblocks), dim3(256), 0, stream>>>(
        ub_src, ub_dst, bu_src, bu_dst, nE, pblocks, part0, part1, bcnt,
        x_user, x_badge, W1_ub_s, a1_ub_s, W1_bu_d, a1_bu_d,
        W1_bu_s, a1_bu_s, W1_ub_d, a1_ub_d,
        hs_u1, as_u1, ad_u1, hs_b1, as_b1, ad_b1, NU, NB, gNU,
        2 * pblocks, 0);
    k_sort2_both<<<dim3(2 * NHALF), dim3(512), 0, stream>>>(
        part0, part1, bcnt, col_ub, col_bu, rp2_ub, rp2_bu);
    k_stageA<<<dim3(gNU + gNB), dim3(256), 0, stream>>>(
        ub_src, ub_dst, bu_src, bu_dst, nE, pblocks, part0, part1, bcnt,
        x_user, x_badge, W1_ub_s, a1_ub_s, W1_bu_d, a1_bu_d,
        W1_bu_s, a1_bu_s, W1_ub_d, a1_ub_d,
        hs_u1, as_u1, ad_u1, hs_b1, as_b1, ad_b1, NU, NB, gNU,
        0, gNU + gNB);
  }
  k_megaL1<<<dim3(ubBlocks + buBlocks), dim3(256), 0, stream>>>(
      rp2_ub, col_ub, a1_ub_s, ad_b1, hs_u1, acc_sl, se_sl,
      rp2_bu, col_bu, a1_bu_s, ad_u1, hs_b1,
      b1_bu, W2_ub_s, a2_ub_s, W2_bu_d, a2_bu_d,
      pk_u, NB, NU, ubBlocks);
  k_finL1b<<<dim3(gNB), dim3(256), 0, stream>>>(
      acc_sl, se_sl, b1_ub, W2_bu_s, a2_bu_s, W2_ub_d, a2_ub_d, pk_b, NB);
  k_gatherL2<<<dim3(g0 + g1), dim3(256), 0, stream>>>(
      rp2_ub, col_ub, rp2_bu, col_bu, pk_u, pk_b, b2_ub, b2_bu, ob, ou, NB, NU, g0);
}

// Round 9
// 422.417 us; speedup vs baseline: 1.0400x; 1.0086x over previous
//
#include <hip/hip_runtime.h>
#include <hip/hip_fp16.h>
#include <math.h>

// HeteroGNN: 2-layer bipartite single-head GAT (users<->badges).
// R21 (from R20 @426us WIN; WRITE model confirmed 60.6->53.8MB. Knob
// exhausted: writes ~1.1x floor, LDS at static limit. stageA still reads
// the edge stream TWICE and burns 17 barriers in the scan):
//   - REGISTER-STAGED SINGLE-READ partition: dst+src int4 loaded ONCE into
//     int4 dreg[10]/sreg[10] (fully unrolled -> stays in VGPRs), hist and
//     scatter both run from regs. Second global pass eliminated (~40MB).
//   - SHFL SCAN: 4-wave __shfl_up scan + 4-entry cross-wave fixup =
//     2 barriers instead of 17.
//   - PART_PER 10240 = 256x40 (exact reg fit); per rounded to x4 in-kernel.
// Everything else identical to R20 (pair-gather megaL1 w/ alpha-via-dot,
// stageA interleave, XCD-pinned shards, packed-float4 L2 gather).

#define NEG_SLOPE 0.2f
#define PART_PER 10240
#define NBC 196
#define CAPC 27072
#define NHALF 392
#define CAPH 13824
#define SHARD_DIV 50000

__device__ __forceinline__ float lrelu(float x) { return x > 0.f ? x : NEG_SLOPE * x; }

// ---------------- stage A: coarse partition (both graphs) + L1 node transforms ----------------
__global__ void k_stageA(
    const int* __restrict__ src0, const int* __restrict__ dst0,
    const int* __restrict__ src1, const int* __restrict__ dst1,
    int nE, int pblocks, unsigned* __restrict__ part0, unsigned* __restrict__ part1,
    int* __restrict__ bcnt,
    const float* __restrict__ xu, const float* __restrict__ xb,
    const float* __restrict__ Wub_s, const float* __restrict__ aub_s,
    const float* __restrict__ Wbu_d, const float* __restrict__ abu_d,
    const float* __restrict__ Wbu_s, const float* __restrict__ abu_s,
    const float* __restrict__ Wub_d, const float* __restrict__ aub_d,
    __half* __restrict__ hs_u, float* __restrict__ as_u, float* __restrict__ ad_u,
    __half* __restrict__ hs_b, float* __restrict__ as_b, float* __restrict__ ad_b,
    int NU, int NB, int gNU, int partBlocks, int nodeBlocks) {
  union Sm {
    struct { unsigned s_sorted[PART_PER]; int h[257]; int ws[4]; int resb[256]; int cur[256]; } p;
    struct { float sW[64 * 16]; float sa[16]; float sv[64]; } n;
  };
  __shared__ Sm sm;
  int t = threadIdx.x;
  // ---- interleave mapping: 2 partition blocks : 1 node block ----
  int b = blockIdx.x;
  int k = min(nodeBlocks, partBlocks / 2);
  int inter = 3 * k;
  int partIdx = -1, nodeIdx = -1;
  if (b < inter) {
    if ((b % 3) == 2) nodeIdx = b / 3;
    else partIdx = (b / 3) * 2 + (b % 3);
  } else {
    int rem = b - inter;
    int ptail = partBlocks - 2 * k;
    if (rem < ptail) partIdx = 2 * k + rem;
    else nodeIdx = k + (rem - ptail);
  }
  if (partIdx >= 0) {
    // ===== partition branch (register-staged single-read) =====
    int gb = partIdx;
    const int* src; const int* dst; unsigned* part; int* bc; int shift; int mask;
    if (gb < pblocks) { src = src0; dst = dst0; part = part0; bc = bcnt; shift = 8; mask = 255; }
    else { gb -= pblocks; src = src1; dst = dst1; part = part1; bc = bcnt + 256; shift = 10; mask = 1023; }
    int per = (((nE + pblocks - 1) / pblocks) + 3) & ~3;   // x4 for int4 alignment
    int beg = gb * per;
    int end = min(beg + per, nE);
    int cnt = end - beg;
    sm.p.h[t] = 0;
    __syncthreads();
    // single-read pass: load dst+src once into regs, hist from regs
    int4 dreg[10], sreg[10];
#pragma unroll
    for (int ii = 0; ii < 10; ++ii) {
      int i = beg + t * 4 + ii * 1024;
      if (i + 3 < end) {
        dreg[ii] = *(const int4*)(dst + i);
        sreg[ii] = *(const int4*)(src + i);
        atomicAdd(&sm.p.h[dreg[ii].x >> shift], 1);
        atomicAdd(&sm.p.h[dreg[ii].y >> shift], 1);
        atomicAdd(&sm.p.h[dreg[ii].z >> shift], 1);
        atomicAdd(&sm.p.h[dreg[ii].w >> shift], 1);
      } else {
        dreg[ii].x = dreg[ii].y = dreg[ii].z = dreg[ii].w = -1;
        sreg[ii].x = sreg[ii].y = sreg[ii].z = sreg[ii].w = 0;
        if (i < end) {
          int m = end - i;  // 1..3
          dreg[ii].x = dst[i]; sreg[ii].x = src[i];
          atomicAdd(&sm.p.h[dreg[ii].x >> shift], 1);
          if (m > 1) { dreg[ii].y = dst[i + 1]; sreg[ii].y = src[i + 1];
                       atomicAdd(&sm.p.h[dreg[ii].y >> shift], 1); }
          if (m > 2) { dreg[ii].z = dst[i + 2]; sreg[ii].z = src[i + 2];
                       atomicAdd(&sm.p.h[dreg[ii].z >> shift], 1); }
        }
      }
    }
    __syncthreads();
    // shfl-based block scan (2 barriers total)
    int v = sm.p.h[t];
    int x = v;
#pragma unroll
    for (int o = 1; o < 64; o <<= 1) {
      int y = __shfl_up(x, o, 64);
      if ((t & 63) >= o) x += y;
    }
    if ((t & 63) == 63) sm.p.ws[t >> 6] = x;
    __syncthreads();
    int wpre = 0;
#pragma unroll
    for (int w = 0; w < 3; ++w) if ((t >> 6) > w) wpre += sm.p.ws[w];
    int incl = x + wpre;
    int excl = incl - v;
    sm.p.resb[t] = (t < NBC && v > 0) ? atomicAdd(&bc[t], v) : 0;
    sm.p.h[t] = excl;
    sm.p.cur[t] = excl;
    if (t == 255) sm.p.h[256] = excl + v;
    __syncthreads();
    // scatter from regs (no global re-read)
#pragma unroll
    for (int ii = 0; ii < 10; ++ii) {
      int i = beg + t * 4 + ii * 1024;
      if (i + 3 < end) {
        int r, d;
        d = dreg[ii].x; r = atomicAdd(&sm.p.cur[d >> shift], 1);
        sm.p.s_sorted[r] = ((unsigned)(d & mask) << 18) | (unsigned)sreg[ii].x;
        d = dreg[ii].y; r = atomicAdd(&sm.p.cur[d >> shift], 1);
        sm.p.s_sorted[r] = ((unsigned)(d & mask) << 18) | (unsigned)sreg[ii].y;
        d = dreg[ii].z; r = atomicAdd(&sm.p.cur[d >> shift], 1);
        sm.p.s_sorted[r] = ((unsigned)(d & mask) << 18) | (unsigned)sreg[ii].z;
        d = dreg[ii].w; r = atomicAdd(&sm.p.cur[d >> shift], 1);
        sm.p.s_sorted[r] = ((unsigned)(d & mask) << 18) | (unsigned)sreg[ii].w;
      } else if (i < end) {
        int m = end - i;
        int r, d;
        d = dreg[ii].x; r = atomicAdd(&sm.p.cur[d >> shift], 1);
        sm.p.s_sorted[r] = ((unsigned)(d & mask) << 18) | (unsigned)sreg[ii].x;
        if (m > 1) { d = dreg[ii].y; r = atomicAdd(&sm.p.cur[d >> shift], 1);
                     sm.p.s_sorted[r] = ((unsigned)(d & mask) << 18) | (unsigned)sreg[ii].y; }
        if (m > 2) { d = dreg[ii].z; r = atomicAdd(&sm.p.cur[d >> shift], 1);
                     sm.p.s_sorted[r] = ((unsigned)(d & mask) << 18) | (unsigned)sreg[ii].z; }
      }
    }
    __syncthreads();
    // flush: 4 concurrent binary-search chains per thread (ILP)
    for (int i = t; i < cnt; i += 1024) {
      int i1 = i + 256, i2 = i + 512, i3 = i + 768;
      int lo0 = 0, lo1 = 0, lo2 = 0, lo3 = 0;
      int hi0 = 256, hi1 = 256, hi2 = 256, hi3 = 256;
#pragma unroll
      for (int s = 0; s < 8; ++s) {
        int m0 = (lo0 + hi0) >> 1; if (sm.p.h[m0] <= i)  lo0 = m0; else hi0 = m0;
        int m1 = (lo1 + hi1) >> 1; if (sm.p.h[m1] <= i1) lo1 = m1; else hi1 = m1;
        int m2 = (lo2 + hi2) >> 1; if (sm.p.h[m2] <= i2) lo2 = m2; else hi2 = m2;
        int m3 = (lo3 + hi3) >> 1; if (sm.p.h[m3] <= i3) lo3 = m3; else hi3 = m3;
      }
      { int p = sm.p.resb[lo0] + (i - sm.p.h[lo0]);
        if (p < CAPC) part[(size_t)lo0 * CAPC + p] = sm.p.s_sorted[i]; }
      if (i1 < cnt) { int p = sm.p.resb[lo1] + (i1 - sm.p.h[lo1]);
        if (p < CAPC) part[(size_t)lo1 * CAPC + p] = sm.p.s_sorted[i1]; }
      if (i2 < cnt) { int p = sm.p.resb[lo2] + (i2 - sm.p.h[lo2]);
        if (p < CAPC) part[(size_t)lo2 * CAPC + p] = sm.p.s_sorted[i2]; }
      if (i3 < cnt) { int p = sm.p.resb[lo3] + (i3 - sm.p.h[lo3]);
        if (p < CAPC) part[(size_t)lo3 * CAPC + p] = sm.p.s_sorted[i3]; }
    }
    return;
  }
  // ===== nodes branch =====
  int blk = nodeIdx;
  bool us = blk < gNU;
  const float* x  = us ? xu : xb;
  const float* Ws = us ? Wub_s : Wbu_s;
  const float* As = us ? aub_s : abu_s;
  const float* Wd = us ? Wbu_d : Wub_d;
  const float* Ad = us ? abu_d : aub_d;
  __half* hs = us ? hs_u : hs_b;
  float* als = us ? as_u : as_b;
  float* ald = us ? ad_u : ad_b;
  int N = us ? NU : NB;
  for (int i = t; i < 64 * 16; i += 256) sm.n.sW[i] = Ws[i];
  if (t < 16) sm.n.sa[t] = As[t];
  if (t < 64) {
    float s = 0.f;
    for (int c = 0; c < 16; ++c) s += Wd[t * 16 + c] * Ad[c];
    sm.n.sv[t] = s;
  }
  __syncthreads();
  int n = (us ? blk : blk - gNU) * 256 + t;
  if (n >= N) return;
  float acc[16];
#pragma unroll
  for (int c = 0; c < 16; ++c) acc[c] = 0.f;
  float ad = 0.f;
  const float4* xr4 = (const float4*)(x + (size_t)n * 64);
#pragma unroll 4
  for (int f4 = 0; f4 < 16; ++f4) {
    float4 xv4 = xr4[f4];
    float xv[4] = {xv4.x, xv4.y, xv4.z, xv4.w};
#pragma unroll
    for (int q = 0; q < 4; ++q) {
      int f = f4 * 4 + q;
#pragma unroll
      for (int c = 0; c < 16; ++c) acc[c] += xv[q] * sm.n.sW[f * 16 + c];
      ad += xv[q] * sm.n.sv[f];
    }
  }
  float al = 0.f;
#pragma unroll
  for (int c = 0; c < 16; ++c) {
    hs[(size_t)n * 16 + c] = __float2half(acc[c]);
    al += acc[c] * sm.n.sa[c];
  }
  als[n] = al;
  ald[n] = ad;
}

// ---------------- CSR stage 2: half-bucket sort, both graphs ----------------
__global__ void k_sort2_both(const unsigned* __restrict__ part0,
                             const unsigned* __restrict__ part1,
                             const int* __restrict__ bcnt,
                             int* __restrict__ col0, int* __restrict__ col1,
                             int* __restrict__ rp0, int* __restrict__ rp1) {
  __shared__ unsigned s_sorted[CAPH];
  __shared__ int hist[512];
  __shared__ int ps[512];
  __shared__ int cur[512];
  __shared__ int s_tot;
  int bb = blockIdx.x;
  const unsigned* part; const int* bc; int* col; int* rp;
  int hsh, hmask, ns, sdiv;
  if (bb < NHALF) { part = part0; bc = bcnt; col = col0; rp = rp0;
                    hsh = 7; hmask = 127; ns = 4; sdiv = SHARD_DIV; }
  else { bb -= NHALF; part = part1; bc = bcnt + 256; col = col1; rp = rp1;
         hsh = 9; hmask = 511; ns = 1; sdiv = 1 << 30; }
  int t = threadIdx.x;
  int f = bb >> 1;
  int half = bb & 1;
  int cnt = min(bc[f], CAPC);
  int cnt4 = cnt & ~3;
  int slot = bb * CAPH;
  const unsigned* pp = part + (size_t)f * CAPC;
  hist[t] = 0;
  __syncthreads();
  for (int i = t * 4; i + 3 < cnt; i += 2048) {
    uint4 e4 = *(const uint4*)(pp + i);
    unsigned ee[4] = {e4.x, e4.y, e4.z, e4.w};
#pragma unroll
    for (int q = 0; q < 4; ++q) {
      int dl = (int)(ee[q] >> 18);
      if ((dl >> hsh) == half) {
        int sv = (int)(ee[q] & 0x3FFFFu);
        int bin = (ns == 4) ? ((dl & hmask) << 2) + sv / sdiv : (dl & hmask);
        atomicAdd(&hist[bin], 1);
      }
    }
  }
  for (int i = cnt4 + t; i < cnt; i += 512) {
    unsigned e = pp[i];
    int dl = (int)(e >> 18);
    if ((dl >> hsh) == half) {
      int sv = (int)(e & 0x3FFFFu);
      int bin = (ns == 4) ? ((dl & hmask) << 2) + sv / sdiv : (dl & hmask);
      atomicAdd(&hist[bin], 1);
    }
  }
  __syncthreads();
  int v = hist[t];
  ps[t] = v;
  __syncthreads();
  for (int off = 1; off < 512; off <<= 1) {
    int u = (t >= off) ? ps[t - off] : 0;
    __syncthreads();
    ps[t] += u;
    __syncthreads();
  }
  int excl = ps[t] - v;
  rp[bb * 513 + t] = slot + excl;
  if (t == 511) {
    int tot = min(ps[511], CAPH);
    rp[bb * 513 + 512] = slot + tot;
    s_tot = tot;
  }
  cur[t] = excl;
  __syncthreads();
  for (int i = t * 4; i + 3 < cnt; i += 2048) {
    uint4 e4 = *(const uint4*)(pp + i);
    unsigned ee[4] = {e4.x, e4.y, e4.z, e4.w};
#pragma unroll
    for (int q = 0; q < 4; ++q) {
      int dl = (int)(ee[q] >> 18);
      if ((dl >> hsh) == half) {
        int sv = (int)(ee[q] & 0x3FFFFu);
        int bin = (ns == 4) ? ((dl & hmask) << 2) + sv / sdiv : (dl & hmask);
        int r = atomicAdd(&cur[bin], 1);
        if (r < CAPH) s_sorted[r] = (unsigned)sv;
      }
    }
  }
  for (int i = cnt4 + t; i < cnt; i += 512) {
    unsigned e = pp[i];
    int dl = (int)(e >> 18);
    if ((dl >> hsh) == half) {
      int sv = (int)(e & 0x3FFFFu);
      int bin = (ns == 4) ? ((dl & hmask) << 2) + sv / sdiv : (dl & hmask);
      int r = atomicAdd(&cur[bin], 1);
      if (r < CAPH) s_sorted[r] = (unsigned)sv;
    }
  }
  __syncthreads();
  int tot = s_tot;
  for (int i = t; i < tot; i += 512) col[slot + i] = (int)s_sorted[i];
}

// ---------------- mega layer-1 gather (8-lane paired groups) ----------------
// Each edge owned by a lane PAIR: lane h loads 16B half of the 32B hs row in
// one instruction (same 64B line as partner -> TA merges to 1 line request).
// alpha = dot(hs_row, a1_s) computed in-register (partial 8-dot + pair
// shfl_xor) -> no as[] gather at all. 2-stage pipeline on col+payload.
__device__ __forceinline__ void gat_pair8(
    const int* __restrict__ col, const __half* __restrict__ hs,
    int beg, int end, int j, float adv, const float (&sa)[8],
    float (&acc)[8], float& se) {
  int h = j & 1;
  int k0 = beg + (j >> 1);
  if (k0 >= end) return;
  int sv0 = col[k0];
  int k1 = k0 + 4;
  int sv1 = (k1 < end) ? col[k1] : -1;
  uint4 hv0 = *(const uint4*)(hs + (size_t)sv0 * 16 + h * 8);
  for (;;) {
    // issue next edge's payload + col for i+2
    uint4 hv1 = hv0;
    int sv2 = -1;
    int k2 = k1 + 4;
    if (sv1 >= 0) {
      hv1 = *(const uint4*)(hs + (size_t)sv1 * 16 + h * 8);
      sv2 = (k2 < end) ? col[k2] : -1;
    }
    // consume current edge
    union { uint4 v; __half hh[8]; } b;
    b.v = hv0;
    float f[8];
    float p = 0.f;
#pragma unroll
    for (int cc = 0; cc < 8; ++cc) {
      f[cc] = __half2float(b.hh[cc]);
      p += f[cc] * sa[cc];
    }
    float afull = p + __shfl_xor(p, 1, 8);
    float w = __expf(lrelu(afull + adv));
    se += w;
#pragma unroll
    for (int cc = 0; cc < 8; ++cc) acc[cc] += w * f[cc];
    if (sv1 < 0) break;
    hv0 = hv1;
    sv1 = sv2;
    k1 = k2;
  }
}

__global__ void k_megaL1(
    const int* __restrict__ rp_ub, const int* __restrict__ col_ub,
    const float* __restrict__ a1s_ub, const float* __restrict__ ad_b,
    const __half* __restrict__ hs_u,
    float* __restrict__ acc_sl, float* __restrict__ se_sl,
    const int* __restrict__ rp_bu, const int* __restrict__ col_bu,
    const float* __restrict__ a1s_bu, const float* __restrict__ ad_u,
    const __half* __restrict__ hs_b,
    const float* __restrict__ b1bu,
    const float* __restrict__ W2ub_s, const float* __restrict__ a2ub_s,
    const float* __restrict__ W2bu_d, const float* __restrict__ a2bu_d,
    float4* __restrict__ pk_u, int NB, int NU, int ubBlocks) {
  __shared__ float sW2[32], sa2[2], sv2[16], sb1[16], sAub[16], sAbu[16];
  int t = threadIdx.x;
  if (t < 32) sW2[t] = W2ub_s[t];
  if (t < 2) sa2[t] = a2ub_s[t];
  if (t < 16) {
    float s = 0.f;
    for (int cc = 0; cc < 2; ++cc) s += W2bu_d[t * 2 + cc] * a2bu_d[cc];
    sv2[t] = s;
    sb1[t] = b1bu[t];
    sAub[t] = a1s_ub[t];
    sAbu[t] = a1s_bu[t];
  }
  __syncthreads();
  int b = blockIdx.x;
  int j = t & 7;
  int h = j & 1;
  if (b < ubBlocks) {
    // 32 badges per block, one shard per block, xcd-pinned
    int xcd = b & 7;
    int s = xcd >> 1;
    int sub = ((b >> 3) << 1) | (xcd & 1);
    int n = sub * 32 + (t >> 3);
    if (n >= NB) return;
    int base = (n >> 7) * 513 + (n & 127) * 4 + s;
    int beg = rp_ub[base], end = rp_ub[base + 1];
    float adv = ad_b[n];
    float sa[8];
#pragma unroll
    for (int cc = 0; cc < 8; ++cc) sa[cc] = sAub[h * 8 + cc];
    float acc[8];
#pragma unroll
    for (int cc = 0; cc < 8; ++cc) acc[cc] = 0.f;
    float se = 0.f;
    gat_pair8(col_ub, hs_u, beg, end, j, adv, sa, acc, se);
#pragma unroll
    for (int m = 2; m < 8; m <<= 1) {
      se += __shfl_xor(se, m, 8);
#pragma unroll
      for (int cc = 0; cc < 8; ++cc) acc[cc] += __shfl_xor(acc[cc], m, 8);
    }
    if (j < 2) {
      float* o = acc_sl + ((size_t)s * NB + n) * 16 + h * 8;
#pragma unroll
      for (int cc = 0; cc < 8; ++cc) o[cc] = acc[cc];
      if (j == 0) se_sl[s * NB + n] = se;
    }
  } else {
    int n = (b - ubBlocks) * 32 + (t >> 3);
    if (n >= NU) return;
    int base = (n >> 9) * 513 + (n & 511);
    int beg = rp_bu[base], end = rp_bu[base + 1];
    float adv = ad_u[n];
    float sa[8];
#pragma unroll
    for (int cc = 0; cc < 8; ++cc) sa[cc] = sAbu[h * 8 + cc];
    float acc[8];
#pragma unroll
    for (int cc = 0; cc < 8; ++cc) acc[cc] = 0.f;
    float se = 0.f;
    gat_pair8(col_bu, hs_b, beg, end, j, adv, sa, acc, se);
#pragma unroll
    for (int m = 2; m < 8; m <<= 1) {
      se += __shfl_xor(se, m, 8);
#pragma unroll
      for (int cc = 0; cc < 8; ++cc) acc[cc] += __shfl_xor(acc[cc], m, 8);
    }
    // inline L2 user transform: each half computes partials over its 8 chans
    float inv = 1.f / (se + 1e-16f);
    float ph0 = 0.f, ph1 = 0.f, padv = 0.f;
#pragma unroll
    for (int cc = 0; cc < 8; ++cc) {
      int c = h * 8 + cc;
      float xv = fmaxf(acc[cc] * inv + sb1[c], 0.f);
      ph0 += xv * sW2[c * 2];
      ph1 += xv * sW2[c * 2 + 1];
      padv += xv * sv2[c];
    }
    ph0 += __shfl_xor(ph0, 1, 8);
    ph1 += __shfl_xor(ph1, 1, 8);
    padv += __shfl_xor(padv, 1, 8);
    if (j == 0)
      pk_u[n] = make_float4(ph0 * sa2[0] + ph1 * sa2[1], ph0, ph1, padv);
  }
}

// ---------------- finalize badges + inline layer-2 badge transform ----------------
__global__ void k_finL1b(
    const float* __restrict__ acc_sl, const float* __restrict__ se_sl,
    const float* __restrict__ b1ub,
    const float* __restrict__ W2bu_s, const float* __restrict__ a2bu_s,
    const float* __restrict__ W2ub_d, const float* __restrict__ a2ub_d,
    float4* __restrict__ pk_b, int NB) {
  __shared__ float sW2[32], sa2[2], sv2[16], sb1[16];
  int t = threadIdx.x;
  if (t < 32) sW2[t] = W2bu_s[t];
  if (t < 2) sa2[t] = a2bu_s[t];
  if (t < 16) {
    float s = 0.f;
    for (int cc = 0; cc < 2; ++cc) s += W2ub_d[t * 2 + cc] * a2ub_d[cc];
    sv2[t] = s;
    sb1[t] = b1ub[t];
  }
  __syncthreads();
  int n = blockIdx.x * 256 + t;
  if (n >= NB) return;
  float a[16];
#pragma unroll
  for (int c = 0; c < 16; ++c) a[c] = 0.f;
  float se = 0.f;
  for (int s = 0; s < 4; ++s) {
    const float4* p = (const float4*)(acc_sl + ((size_t)s * NB + n) * 16);
    float4 v0 = p[0], v1 = p[1], v2 = p[2], v3 = p[3];
    a[0] += v0.x; a[1] += v0.y; a[2] += v0.z; a[3] += v0.w;
    a[4] += v1.x; a[5] += v1.y; a[6] += v1.z; a[7] += v1.w;
    a[8] += v2.x; a[9] += v2.y; a[10] += v2.z; a[11] += v2.w;
    a[12] += v3.x; a[13] += v3.y; a[14] += v3.z; a[15] += v3.w;
    se += se_sl[s * NB + n];
  }
  float inv = 1.f / (se + 1e-16f);
  float h0 = 0.f, h1 = 0.f, advn = 0.f;
#pragma unroll
  for (int c = 0; c < 16; ++c) {
    float xv = fmaxf(a[c] * inv + sb1[c], 0.f);
    h0 += xv * sW2[c * 2];
    h1 += xv * sW2[c * 2 + 1];
    advn += xv * sv2[c];
  }
  pk_b[n] = make_float4(h0 * sa2[0] + h1 * sa2[1], h0, h1, advn);
}

// ---------------- fused layer-2 output gathers (packed tables, 4-lane groups, 2-stage pipeline) ----------------
__global__ void k_gatherL2(
    const int* __restrict__ rp0, const int* __restrict__ col0,
    const int* __restrict__ rp1, const int* __restrict__ col1,
    const float4* __restrict__ pk_u, const float4* __restrict__ pk_b,
    const float* __restrict__ b2ub, const float* __restrict__ b2bu,
    float* __restrict__ ob, float* __restrict__ ou,
    int NB, int NU, int g0) {
  int blk = blockIdx.x;
  const int *rp, *col; const float4 *pksrc, *pkown; const float* bb; float* out;
  int N, lsh, nsg;
  if (blk < g0) { rp = rp0; col = col0; pksrc = pk_u; pkown = pk_b; bb = b2ub;
                  out = ob; N = NB; lsh = 7; nsg = 4; }
  else { blk -= g0; rp = rp1; col = col1; pksrc = pk_b; pkown = pk_u; bb = b2bu;
         out = ou; N = NU; lsh = 9; nsg = 1; }
  int n = blk * 64 + (threadIdx.x >> 2);
  int j = threadIdx.x & 3;
  if (n >= N) return;
  int base = (n >> lsh) * 513 + (n & ((1 << lsh) - 1)) * nsg;
  int beg = rp[base], end = rp[base + nsg];
  float adv = pkown[n].w;
  float a0 = 0.f, a1 = 0.f, se = 0.f;
  // stride-4 coalesced, 2-stage pipeline (payload for i+1 issued before
  // consuming i; col prefetched for i+2)
  int k0 = beg + j;
  if (k0 < end) {
    int c0 = col[k0];
    int k1 = k0 + 4;
    int c1 = (k1 < end) ? col[k1] : -1;
    float4 p0 = pksrc[c0];
    for (;;) {
      float4 p1 = p0;
      int c2 = -1;
      int k2 = k1 + 4;
      if (c1 >= 0) {
        p1 = pksrc[c1];
        c2 = (k2 < end) ? col[k2] : -1;
      }
      float w = __expf(lrelu(p0.x + adv));
      se += w;
      a0 += w * p0.y;
      a1 += w * p0.z;
      if (c1 < 0) break;
      p0 = p1;
      c1 = c2;
      k1 = k2;
    }
  }
#pragma unroll
  for (int m = 1; m < 4; m <<= 1) {
    se += __shfl_xor(se, m, 4);
    a0 += __shfl_xor(a0, m, 4);
    a1 += __shfl_xor(a1, m, 4);
  }
  if (j == 0) {
    float inv = 1.f / (se + 1e-16f);
    out[(size_t)n * 2] = a0 * inv + bb[0];
    out[(size_t)n * 2 + 1] = a1 * inv + bb[1];
  }
}

extern "C" void kernel_launch(void* const* d_in, const int* in_sizes, int n_in,
                              void* d_out, int out_size, void* d_ws, size_t ws_size,
                              hipStream_t stream) {
  const int NU = 200000, NB = 50000;
  const float* x_user  = (const float*)d_in[0];
  const float* x_badge = (const float*)d_in[1];
  const int* ub_src = (const int*)d_in[2];
  const int* ub_dst = (const int*)d_in[3];
  const int* bu_src = (const int*)d_in[4];
  const int* bu_dst = (const int*)d_in[5];
  const int nE = in_sizes[2];

  const float* W1_ub_s = (const float*)d_in[8];
  const float* W1_ub_d = (const float*)d_in[9];
  const float* a1_ub_s = (const float*)d_in[10];
  const float* a1_ub_d = (const float*)d_in[11];
  const float* b1_ub   = (const float*)d_in[12];
  const float* W2_ub_s = (const float*)d_in[13];
  const float* W2_ub_d = (const float*)d_in[14];
  const float* a2_ub_s = (const float*)d_in[15];
  const float* a2_ub_d = (const float*)d_in[16];
  const float* b2_ub   = (const float*)d_in[17];
  const float* W1_bu_s = (const float*)d_in[18];
  const float* W1_bu_d = (const float*)d_in[19];
  const float* a1_bu_s = (const float*)d_in[20];
  const float* a1_bu_d = (const float*)d_in[21];
  const float* b1_bu   = (const float*)d_in[22];
  const float* W2_bu_s = (const float*)d_in[23];
  const float* W2_bu_d = (const float*)d_in[24];
  const float* a2_bu_s = (const float*)d_in[25];
  const float* a2_bu_d = (const float*)d_in[26];
  const float* b2_bu   = (const float*)d_in[27];

  const int pblocks = (nE + PART_PER - 1) / PART_PER;
  const int gNU = (NU + 255) / 256;        // 782
  const int gNB = (NB + 255) / 256;        // 196

  // ---- workspace carve-up ----
  char* wsb = (char*)d_ws;
  size_t off = 0;
  auto ialloc = [&](size_t n) { int* p = (int*)(wsb + off); off += n * 4; return p; };
  int* rp2_ub = ialloc((size_t)NHALF * 513);
  int* rp2_bu = ialloc((size_t)NHALF * 513);
  int* bcnt   = ialloc(512);
  int* col_ub = ialloc((size_t)NHALF * CAPH);
  int* col_bu = ialloc((size_t)NHALF * CAPH);
  off = (off + 15) & ~(size_t)15;
  const size_t partBytes = (size_t)2 * NBC * CAPC * 4;
  const size_t nodeBytes = (size_t)NU * 32 + (size_t)NB * 32 +
                           (size_t)(NU + NB) * 8 + 1024;
  bool fused = ws_size >= off + partBytes + nodeBytes + 4096;
  char* partBase = wsb + off;
  char* nodeBase = fused ? (partBase + partBytes) : partBase;
  unsigned* part0 = (unsigned*)partBase;
  unsigned* part1 = part0 + (size_t)NBC * CAPC;
  size_t poff = 0;
  auto falloc = [&](size_t n) { float* p = (float*)(nodeBase + poff); poff += n * 4; return p; };
  auto halloc = [&](size_t n) { __half* p = (__half*)(nodeBase + poff); poff += n * 2; return p; };
  __half* hs_u1 = halloc((size_t)NU * 16);
  __half* hs_b1 = halloc((size_t)NB * 16);
  float* as_u1  = falloc(NU);
  float* ad_u1  = falloc(NU);
  float* as_b1  = falloc(NB);
  float* ad_b1  = falloc(NB);
  poff = (poff + 15) & ~(size_t)15;
  float4* pk_u  = (float4*)(nodeBase + poff); poff += (size_t)NU * 16;
  float4* pk_b  = (float4*)(nodeBase + poff); poff += (size_t)NB * 16;
  char* accBase = fused ? partBase : (nodeBase + ((poff + 15) & ~(size_t)15));
  float* acc_sl = (float*)accBase;
  float* se_sl  = (float*)(accBase + (size_t)4 * NB * 16 * 4);

  float* ou = (float*)d_out;                   // [NU,2]
  float* ob = (float*)d_out + (size_t)NU * 2;  // [NB,2]

  // megaL1: 8-lane paired groups -> 32 nodes per 256-thread block
  const int chunksB = (NB + 31) / 32;                 // 1563
  const int ubBlocks = ((chunksB + 1) / 2) * 8;       // 6256 (xcd-pinned pairs)
  const int buBlocks = (NU + 31) / 32;                // 6250
  // gatherL2: 4-lane groups -> 64 nodes per block
  const int g0 = (NB + 63) / 64;                      // 782
  const int g1 = (NU + 63) / 64;                      // 3125

  hipMemsetAsync(bcnt, 0, 512 * 4, stream);
  if (fused) {
    k_stageA<<<dim3(2 * pblocks + gNU + gNB), dim3(256), 0, stream>>>(
        ub_src, ub_dst, bu_src, bu_dst, nE, pblocks, part0, part1, bcnt,
        x_user, x_badge, W1_ub_s, a1_ub_s, W1_bu_d, a1_bu_d,
        W1_bu_s, a1_bu_s, W1_ub_d, a1_ub_d,
        hs_u1, as_u1, ad_u1, hs_b1, as_b1, ad_b1, NU, NB, gNU,
        2 * pblocks, gNU + gNB);
    k_sort2_both<<<dim3(2 * NHALF), dim3(512), 0, stream>>>(
        part0, part1, bcnt, col_ub, col_bu, rp2_ub, rp2_bu);
  } else {
    k_stageA<<<dim3(2 * pblocks), dim3(256), 0, stream>>>(
        ub_src, ub_dst, bu_src, bu_dst, nE, pblocks, part0, part1, bcnt,
        x_user, x_badge, W1_ub_s, a1_ub_s, W1_bu_d, a1_bu_d,
        W1_bu_s, a1_bu_s, W1_ub_d, a1_ub_d,
        hs_u1, as_u1, ad_u1, hs_b1, as_b1, ad_b1, NU, NB, gNU,
        2 * pblocks, 0);
    k_sort2_both<<<dim3(2 * NHALF), dim3(512), 0, stream>>>(
        part0, part1, bcnt, col_ub, col_bu, rp2_ub, rp2_bu);
    k_stageA<<<dim3(gNU + gNB), dim3(256), 0, stream>>>(
        ub_src, ub_dst, bu_src, bu_dst, nE, pblocks, part0, part1, bcnt,
        x_user, x_badge, W1_ub_s, a1_ub_s, W1_bu_d, a1_bu_d,
        W1_bu_s, a1_bu_s, W1_ub_d, a1_ub_d,
        hs_u1, as_u1, ad_u1, hs_b1, as_b1, ad_b1, NU, NB, gNU,
        0, gNU + gNB);
  }
  k_megaL1<<<dim3(ubBlocks + buBlocks), dim3(256), 0, stream>>>(
      rp2_ub, col_ub, a1_ub_s, ad_b1, hs_u1, acc_sl, se_sl,
      rp2_bu, col_bu, a1_bu_s, ad_u1, hs_b1,
      b1_bu, W2_ub_s, a2_ub_s, W2_bu_d, a2_bu_d,
      pk_u, NB, NU, ubBlocks);
  k_finL1b<<<dim3(gNB), dim3(256), 0, stream>>>(
      acc_sl, se_sl, b1_ub, W2_bu_s, a2_bu_s, W2_ub_d, a2_ub_d, pk_b, NB);
  k_gatherL2<<<dim3(g0 + g1), dim3(256), 0, stream>>>(
      rp2_ub, col_ub, rp2_bu, col_bu, pk_u, pk_b, b2_ub, b2_bu, ob, ou, NB, NU, g0);
}

// Round 10
// 414.704 us; speedup vs baseline: 1.0594x; 1.0186x over previous
//
#include <hip/hip_runtime.h>
#include <hip/hip_fp16.h>
#include <math.h>

// HeteroGNN: 2-layer bipartite single-head GAT (users<->badges).
// R22 (from R21 @422us WIN; stageA 97->90, FETCH -16MB. stageA now has all
// pipes <30% and both occupancy directions exhausted -> structural limit.
// Next unoptimized kernel: k_sort2_both (est 70-90us, never touched) with
// the same pathology R21 fixed: fragment read 4x (2 halves x 2 passes) and
// an 18-barrier Hillis-Steele scan at 2 blocks/CU):
//   - REGISTER-STAGED sort2: fragment loaded once per half-block into
//     uint4 er[14] (28672 slots >= CAPC; sentinel 0xFFFFFFFF fails the
//     half filter for hsh=7 and 9); hist + scatter both run from regs.
//     Fragment reads 4x -> 2x total.
//   - SHFL SCAN in sort2: 64-wide __shfl_up + 8-entry cross-wave fixup;
//     5 barriers instead of ~21. ps[]/cur[] dropped (reuse hist), -4KB LDS.
// Everything else identical to R21 (reg-staged stageA, pair-gather megaL1
// w/ alpha-via-dot, XCD-pinned shards, packed-float4 L2 gather).

#define NEG_SLOPE 0.2f
#define PART_PER 10240
#define NBC 196
#define CAPC 27072
#define NHALF 392
#define CAPH 13824
#define SHARD_DIV 50000

__device__ __forceinline__ float lrelu(float x) { return x > 0.f ? x : NEG_SLOPE * x; }

// ---------------- stage A: coarse partition (both graphs) + L1 node transforms ----------------
__global__ void k_stageA(
    const int* __restrict__ src0, const int* __restrict__ dst0,
    const int* __restrict__ src1, const int* __restrict__ dst1,
    int nE, int pblocks, unsigned* __restrict__ part0, unsigned* __restrict__ part1,
    int* __restrict__ bcnt,
    const float* __restrict__ xu, const float* __restrict__ xb,
    const float* __restrict__ Wub_s, const float* __restrict__ aub_s,
    const float* __restrict__ Wbu_d, const float* __restrict__ abu_d,
    const float* __restrict__ Wbu_s, const float* __restrict__ abu_s,
    const float* __restrict__ Wub_d, const float* __restrict__ aub_d,
    __half* __restrict__ hs_u, float* __restrict__ as_u, float* __restrict__ ad_u,
    __half* __restrict__ hs_b, float* __restrict__ as_b, float* __restrict__ ad_b,
    int NU, int NB, int gNU, int partBlocks, int nodeBlocks) {
  union Sm {
    struct { unsigned s_sorted[PART_PER]; int h[257]; int ws[4]; int resb[256]; int cur[256]; } p;
    struct { float sW[64 * 16]; float sa[16]; float sv[64]; } n;
  };
  __shared__ Sm sm;
  int t = threadIdx.x;
  // ---- interleave mapping: 2 partition blocks : 1 node block ----
  int b = blockIdx.x;
  int k = min(nodeBlocks, partBlocks / 2);
  int inter = 3 * k;
  int partIdx = -1, nodeIdx = -1;
  if (b < inter) {
    if ((b % 3) == 2) nodeIdx = b / 3;
    else partIdx = (b / 3) * 2 + (b % 3);
  } else {
    int rem = b - inter;
    int ptail = partBlocks - 2 * k;
    if (rem < ptail) partIdx = 2 * k + rem;
    else nodeIdx = k + (rem - ptail);
  }
  if (partIdx >= 0) {
    // ===== partition branch (register-staged single-read) =====
    int gb = partIdx;
    const int* src; const int* dst; unsigned* part; int* bc; int shift; int mask;
    if (gb < pblocks) { src = src0; dst = dst0; part = part0; bc = bcnt; shift = 8; mask = 255; }
    else { gb -= pblocks; src = src1; dst = dst1; part = part1; bc = bcnt + 256; shift = 10; mask = 1023; }
    int per = (((nE + pblocks - 1) / pblocks) + 3) & ~3;   // x4 for int4 alignment
    int beg = gb * per;
    int end = min(beg + per, nE);
    int cnt = end - beg;
    sm.p.h[t] = 0;
    __syncthreads();
    // single-read pass: load dst+src once into regs, hist from regs
    int4 dreg[10], sreg[10];
#pragma unroll
    for (int ii = 0; ii < 10; ++ii) {
      int i = beg + t * 4 + ii * 1024;
      if (i + 3 < end) {
        dreg[ii] = *(const int4*)(dst + i);
        sreg[ii] = *(const int4*)(src + i);
        atomicAdd(&sm.p.h[dreg[ii].x >> shift], 1);
        atomicAdd(&sm.p.h[dreg[ii].y >> shift], 1);
        atomicAdd(&sm.p.h[dreg[ii].z >> shift], 1);
        atomicAdd(&sm.p.h[dreg[ii].w >> shift], 1);
      } else {
        dreg[ii].x = dreg[ii].y = dreg[ii].z = dreg[ii].w = -1;
        sreg[ii].x = sreg[ii].y = sreg[ii].z = sreg[ii].w = 0;
        if (i < end) {
          int m = end - i;  // 1..3
          dreg[ii].x = dst[i]; sreg[ii].x = src[i];
          atomicAdd(&sm.p.h[dreg[ii].x >> shift], 1);
          if (m > 1) { dreg[ii].y = dst[i + 1]; sreg[ii].y = src[i + 1];
                       atomicAdd(&sm.p.h[dreg[ii].y >> shift], 1); }
          if (m > 2) { dreg[ii].z = dst[i + 2]; sreg[ii].z = src[i + 2];
                       atomicAdd(&sm.p.h[dreg[ii].z >> shift], 1); }
        }
      }
    }
    __syncthreads();
    // shfl-based block scan (2 barriers total)
    int v = sm.p.h[t];
    int x = v;
#pragma unroll
    for (int o = 1; o < 64; o <<= 1) {
      int y = __shfl_up(x, o, 64);
      if ((t & 63) >= o) x += y;
    }
    if ((t & 63) == 63) sm.p.ws[t >> 6] = x;
    __syncthreads();
    int wpre = 0;
#pragma unroll
    for (int w = 0; w < 3; ++w) if ((t >> 6) > w) wpre += sm.p.ws[w];
    int incl = x + wpre;
    int excl = incl - v;
    sm.p.resb[t] = (t < NBC && v > 0) ? atomicAdd(&bc[t], v) : 0;
    sm.p.h[t] = excl;
    sm.p.cur[t] = excl;
    if (t == 255) sm.p.h[256] = excl + v;
    __syncthreads();
    // scatter from regs (no global re-read)
#pragma unroll
    for (int ii = 0; ii < 10; ++ii) {
      int i = beg + t * 4 + ii * 1024;
      if (i + 3 < end) {
        int r, d;
        d = dreg[ii].x; r = atomicAdd(&sm.p.cur[d >> shift], 1);
        sm.p.s_sorted[r] = ((unsigned)(d & mask) << 18) | (unsigned)sreg[ii].x;
        d = dreg[ii].y; r = atomicAdd(&sm.p.cur[d >> shift], 1);
        sm.p.s_sorted[r] = ((unsigned)(d & mask) << 18) | (unsigned)sreg[ii].y;
        d = dreg[ii].z; r = atomicAdd(&sm.p.cur[d >> shift], 1);
        sm.p.s_sorted[r] = ((unsigned)(d & mask) << 18) | (unsigned)sreg[ii].z;
        d = dreg[ii].w; r = atomicAdd(&sm.p.cur[d >> shift], 1);
        sm.p.s_sorted[r] = ((unsigned)(d & mask) << 18) | (unsigned)sreg[ii].w;
      } else if (i < end) {
        int m = end - i;
        int r, d;
        d = dreg[ii].x; r = atomicAdd(&sm.p.cur[d >> shift], 1);
        sm.p.s_sorted[r] = ((unsigned)(d & mask) << 18) | (unsigned)sreg[ii].x;
        if (m > 1) { d = dreg[ii].y; r = atomicAdd(&sm.p.cur[d >> shift], 1);
                     sm.p.s_sorted[r] = ((unsigned)(d & mask) << 18) | (unsigned)sreg[ii].y; }
        if (m > 2) { d = dreg[ii].z; r = atomicAdd(&sm.p.cur[d >> shift], 1);
                     sm.p.s_sorted[r] = ((unsigned)(d & mask) << 18) | (unsigned)sreg[ii].z; }
      }
    }
    __syncthreads();
    // flush: 4 concurrent binary-search chains per thread (ILP)
    for (int i = t; i < cnt; i += 1024) {
      int i1 = i + 256, i2 = i + 512, i3 = i + 768;
      int lo0 = 0, lo1 = 0, lo2 = 0, lo3 = 0;
      int hi0 = 256, hi1 = 256, hi2 = 256, hi3 = 256;
#pragma unroll
      for (int s = 0; s < 8; ++s) {
        int m0 = (lo0 + hi0) >> 1; if (sm.p.h[m0] <= i)  lo0 = m0; else hi0 = m0;
        int m1 = (lo1 + hi1) >> 1; if (sm.p.h[m1] <= i1) lo1 = m1; else hi1 = m1;
        int m2 = (lo2 + hi2) >> 1; if (sm.p.h[m2] <= i2) lo2 = m2; else hi2 = m2;
        int m3 = (lo3 + hi3) >> 1; if (sm.p.h[m3] <= i3) lo3 = m3; else hi3 = m3;
      }
      { int p = sm.p.resb[lo0] + (i - sm.p.h[lo0]);
        if (p < CAPC) part[(size_t)lo0 * CAPC + p] = sm.p.s_sorted[i]; }
      if (i1 < cnt) { int p = sm.p.resb[lo1] + (i1 - sm.p.h[lo1]);
        if (p < CAPC) part[(size_t)lo1 * CAPC + p] = sm.p.s_sorted[i1]; }
      if (i2 < cnt) { int p = sm.p.resb[lo2] + (i2 - sm.p.h[lo2]);
        if (p < CAPC) part[(size_t)lo2 * CAPC + p] = sm.p.s_sorted[i2]; }
      if (i3 < cnt) { int p = sm.p.resb[lo3] + (i3 - sm.p.h[lo3]);
        if (p < CAPC) part[(size_t)lo3 * CAPC + p] = sm.p.s_sorted[i3]; }
    }
    return;
  }
  // ===== nodes branch =====
  int blk = nodeIdx;
  bool us = blk < gNU;
  const float* x  = us ? xu : xb;
  const float* Ws = us ? Wub_s : Wbu_s;
  const float* As = us ? aub_s : abu_s;
  const float* Wd = us ? Wbu_d : Wub_d;
  const float* Ad = us ? abu_d : aub_d;
  __half* hs = us ? hs_u : hs_b;
  float* als = us ? as_u : as_b;
  float* ald = us ? ad_u : ad_b;
  int N = us ? NU : NB;
  for (int i = t; i < 64 * 16; i += 256) sm.n.sW[i] = Ws[i];
  if (t < 16) sm.n.sa[t] = As[t];
  if (t < 64) {
    float s = 0.f;
    for (int c = 0; c < 16; ++c) s += Wd[t * 16 + c] * Ad[c];
    sm.n.sv[t] = s;
  }
  __syncthreads();
  int n = (us ? blk : blk - gNU) * 256 + t;
  if (n >= N) return;
  float acc[16];
#pragma unroll
  for (int c = 0; c < 16; ++c) acc[c] = 0.f;
  float ad = 0.f;
  const float4* xr4 = (const float4*)(x + (size_t)n * 64);
#pragma unroll 4
  for (int f4 = 0; f4 < 16; ++f4) {
    float4 xv4 = xr4[f4];
    float xv[4] = {xv4.x, xv4.y, xv4.z, xv4.w};
#pragma unroll
    for (int q = 0; q < 4; ++q) {
      int f = f4 * 4 + q;
#pragma unroll
      for (int c = 0; c < 16; ++c) acc[c] += xv[q] * sm.n.sW[f * 16 + c];
      ad += xv[q] * sm.n.sv[f];
    }
  }
  float al = 0.f;
#pragma unroll
  for (int c = 0; c < 16; ++c) {
    hs[(size_t)n * 16 + c] = __float2half(acc[c]);
    al += acc[c] * sm.n.sa[c];
  }
  als[n] = al;
  ald[n] = ad;
}

// ---------------- CSR stage 2: half-bucket sort, both graphs ----------------
// Register-staged single-read + shfl scan (R22). Each half-block loads the
// full fragment ONCE into uint4 er[14] (28672 slots >= CAPC); sentinel
// 0xFFFFFFFF yields dl=0x3FFF whose (dl>>hsh) is 127/31 != half -> filtered.
__global__ void k_sort2_both(const unsigned* __restrict__ part0,
                             const unsigned* __restrict__ part1,
                             const int* __restrict__ bcnt,
                             int* __restrict__ col0, int* __restrict__ col1,
                             int* __restrict__ rp0, int* __restrict__ rp1) {
  __shared__ unsigned s_sorted[CAPH];
  __shared__ int hist[512];
  __shared__ int ws[8];
  __shared__ int s_tot;
  int bb = blockIdx.x;
  const unsigned* part; const int* bc; int* col; int* rp;
  int hsh, hmask, ns, sdiv;
  if (bb < NHALF) { part = part0; bc = bcnt; col = col0; rp = rp0;
                    hsh = 7; hmask = 127; ns = 4; sdiv = SHARD_DIV; }
  else { bb -= NHALF; part = part1; bc = bcnt + 256; col = col1; rp = rp1;
         hsh = 9; hmask = 511; ns = 1; sdiv = 1 << 30; }
  int t = threadIdx.x;
  int f = bb >> 1;
  int half = bb & 1;
  int cnt = min(bc[f], CAPC);
  int slot = bb * CAPH;
  const unsigned* pp = part + (size_t)f * CAPC;
  // stage fragment into regs (single global read per half-block)
  uint4 er[14];
#pragma unroll
  for (int ii = 0; ii < 14; ++ii) {
    int i = t * 4 + ii * 2048;
    if (i + 3 < cnt) {
      er[ii] = *(const uint4*)(pp + i);
    } else {
      er[ii].x = er[ii].y = er[ii].z = er[ii].w = 0xFFFFFFFFu;
      if (i < cnt) {
        er[ii].x = pp[i];
        if (i + 1 < cnt) er[ii].y = pp[i + 1];
        if (i + 2 < cnt) er[ii].z = pp[i + 2];
      }
    }
  }
  hist[t] = 0;
  __syncthreads();
  // hist from regs
#pragma unroll
  for (int ii = 0; ii < 14; ++ii) {
    unsigned ee[4] = {er[ii].x, er[ii].y, er[ii].z, er[ii].w};
#pragma unroll
    for (int q = 0; q < 4; ++q) {
      int dl = (int)(ee[q] >> 18);
      if ((dl >> hsh) == half) {
        int sv = (int)(ee[q] & 0x3FFFFu);
        int bin = (ns == 4) ? ((dl & hmask) << 2) + sv / sdiv : (dl & hmask);
        atomicAdd(&hist[bin], 1);
      }
    }
  }
  __syncthreads();
  // shfl scan over 512 bins (8 waves of 64 + cross-wave fixup)
  int v = hist[t];
  int x = v;
#pragma unroll
  for (int o = 1; o < 64; o <<= 1) {
    int y = __shfl_up(x, o, 64);
    if ((t & 63) >= o) x += y;
  }
  if ((t & 63) == 63) ws[t >> 6] = x;
  __syncthreads();
  int wpre = 0;
#pragma unroll
  for (int w = 0; w < 7; ++w) if ((t >> 6) > w) wpre += ws[w];
  int incl = x + wpre;
  int excl = incl - v;
  rp[bb * 513 + t] = slot + excl;
  if (t == 511) {
    int tot = min(incl, CAPH);
    rp[bb * 513 + 512] = slot + tot;
    s_tot = tot;
  }
  hist[t] = excl;   // reuse hist as cur[]
  __syncthreads();
  // scatter from regs
#pragma unroll
  for (int ii = 0; ii < 14; ++ii) {
    unsigned ee[4] = {er[ii].x, er[ii].y, er[ii].z, er[ii].w};
#pragma unroll
    for (int q = 0; q < 4; ++q) {
      int dl = (int)(ee[q] >> 18);
      if ((dl >> hsh) == half) {
        int sv = (int)(ee[q] & 0x3FFFFu);
        int bin = (ns == 4) ? ((dl & hmask) << 2) + sv / sdiv : (dl & hmask);
        int r = atomicAdd(&hist[bin], 1);
        if (r < CAPH) s_sorted[r] = (unsigned)sv;
      }
    }
  }
  __syncthreads();
  int tot = s_tot;
  for (int i = t; i < tot; i += 512) col[slot + i] = (int)s_sorted[i];
}

// ---------------- mega layer-1 gather (8-lane paired groups) ----------------
// Each edge owned by a lane PAIR: lane h loads 16B half of the 32B hs row in
// one instruction (same 64B line as partner -> TA merges to 1 line request).
// alpha = dot(hs_row, a1_s) computed in-register (partial 8-dot + pair
// shfl_xor) -> no as[] gather at all. 2-stage pipeline on col+payload.
__device__ __forceinline__ void gat_pair8(
    const int* __restrict__ col, const __half* __restrict__ hs,
    int beg, int end, int j, float adv, const float (&sa)[8],
    float (&acc)[8], float& se) {
  int h = j & 1;
  int k0 = beg + (j >> 1);
  if (k0 >= end) return;
  int sv0 = col[k0];
  int k1 = k0 + 4;
  int sv1 = (k1 < end) ? col[k1] : -1;
  uint4 hv0 = *(const uint4*)(hs + (size_t)sv0 * 16 + h * 8);
  for (;;) {
    // issue next edge's payload + col for i+2
    uint4 hv1 = hv0;
    int sv2 = -1;
    int k2 = k1 + 4;
    if (sv1 >= 0) {
      hv1 = *(const uint4*)(hs + (size_t)sv1 * 16 + h * 8);
      sv2 = (k2 < end) ? col[k2] : -1;
    }
    // consume current edge
    union { uint4 v; __half hh[8]; } b;
    b.v = hv0;
    float f[8];
    float p = 0.f;
#pragma unroll
    for (int cc = 0; cc < 8; ++cc) {
      f[cc] = __half2float(b.hh[cc]);
      p += f[cc] * sa[cc];
    }
    float afull = p + __shfl_xor(p, 1, 8);
    float w = __expf(lrelu(afull + adv));
    se += w;
#pragma unroll
    for (int cc = 0; cc < 8; ++cc) acc[cc] += w * f[cc];
    if (sv1 < 0) break;
    hv0 = hv1;
    sv1 = sv2;
    k1 = k2;
  }
}

__global__ void k_megaL1(
    const int* __restrict__ rp_ub, const int* __restrict__ col_ub,
    const float* __restrict__ a1s_ub, const float* __restrict__ ad_b,
    const __half* __restrict__ hs_u,
    float* __restrict__ acc_sl, float* __restrict__ se_sl,
    const int* __restrict__ rp_bu, const int* __restrict__ col_bu,
    const float* __restrict__ a1s_bu, const float* __restrict__ ad_u,
    const __half* __restrict__ hs_b,
    const float* __restrict__ b1bu,
    const float* __restrict__ W2ub_s, const float* __restrict__ a2ub_s,
    const float* __restrict__ W2bu_d, const float* __restrict__ a2bu_d,
    float4* __restrict__ pk_u, int NB, int NU, int ubBlocks) {
  __shared__ float sW2[32], sa2[2], sv2[16], sb1[16], sAub[16], sAbu[16];
  int t = threadIdx.x;
  if (t < 32) sW2[t] = W2ub_s[t];
  if (t < 2) sa2[t] = a2ub_s[t];
  if (t < 16) {
    float s = 0.f;
    for (int cc = 0; cc < 2; ++cc) s += W2bu_d[t * 2 + cc] * a2bu_d[cc];
    sv2[t] = s;
    sb1[t] = b1bu[t];
    sAub[t] = a1s_ub[t];
    sAbu[t] = a1s_bu[t];
  }
  __syncthreads();
  int b = blockIdx.x;
  int j = t & 7;
  int h = j & 1;
  if (b < ubBlocks) {
    // 32 badges per block, one shard per block, xcd-pinned
    int xcd = b & 7;
    int s = xcd >> 1;
    int sub = ((b >> 3) << 1) | (xcd & 1);
    int n = sub * 32 + (t >> 3);
    if (n >= NB) return;
    int base = (n >> 7) * 513 + (n & 127) * 4 + s;
    int beg = rp_ub[base], end = rp_ub[base + 1];
    float adv = ad_b[n];
    float sa[8];
#pragma unroll
    for (int cc = 0; cc < 8; ++cc) sa[cc] = sAub[h * 8 + cc];
    float acc[8];
#pragma unroll
    for (int cc = 0; cc < 8; ++cc) acc[cc] = 0.f;
    float se = 0.f;
    gat_pair8(col_ub, hs_u, beg, end, j, adv, sa, acc, se);
#pragma unroll
    for (int m = 2; m < 8; m <<= 1) {
      se += __shfl_xor(se, m, 8);
#pragma unroll
      for (int cc = 0; cc < 8; ++cc) acc[cc] += __shfl_xor(acc[cc], m, 8);
    }
    if (j < 2) {
      float* o = acc_sl + ((size_t)s * NB + n) * 16 + h * 8;
#pragma unroll
      for (int cc = 0; cc < 8; ++cc) o[cc] = acc[cc];
      if (j == 0) se_sl[s * NB + n] = se;
    }
  } else {
    int n = (b - ubBlocks) * 32 + (t >> 3);
    if (n >= NU) return;
    int base = (n >> 9) * 513 + (n & 511);
    int beg = rp_bu[base], end = rp_bu[base + 1];
    float adv = ad_u[n];
    float sa[8];
#pragma unroll
    for (int cc = 0; cc < 8; ++cc) sa[cc] = sAbu[h * 8 + cc];
    float acc[8];
#pragma unroll
    for (int cc = 0; cc < 8; ++cc) acc[cc] = 0.f;
    float se = 0.f;
    gat_pair8(col_bu, hs_b, beg, end, j, adv, sa, acc, se);
#pragma unroll
    for (int m = 2; m < 8; m <<= 1) {
      se += __shfl_xor(se, m, 8);
#pragma unroll
      for (int cc = 0; cc < 8; ++cc) acc[cc] += __shfl_xor(acc[cc], m, 8);
    }
    // inline L2 user transform: each half computes partials over its 8 chans
    float inv = 1.f / (se + 1e-16f);
    float ph0 = 0.f, ph1 = 0.f, padv = 0.f;
#pragma unroll
    for (int cc = 0; cc < 8; ++cc) {
      int c = h * 8 + cc;
      float xv = fmaxf(acc[cc] * inv + sb1[c], 0.f);
      ph0 += xv * sW2[c * 2];
      ph1 += xv * sW2[c * 2 + 1];
      padv += xv * sv2[c];
    }
    ph0 += __shfl_xor(ph0, 1, 8);
    ph1 += __shfl_xor(ph1, 1, 8);
    padv += __shfl_xor(padv, 1, 8);
    if (j == 0)
      pk_u[n] = make_float4(ph0 * sa2[0] + ph1 * sa2[1], ph0, ph1, padv);
  }
}

// ---------------- finalize badges + inline layer-2 badge transform ----------------
__global__ void k_finL1b(
    const float* __restrict__ acc_sl, const float* __restrict__ se_sl,
    const float* __restrict__ b1ub,
    const float* __restrict__ W2bu_s, const float* __restrict__ a2bu_s,
    const float* __restrict__ W2ub_d, const float* __restrict__ a2ub_d,
    float4* __restrict__ pk_b, int NB) {
  __shared__ float sW2[32], sa2[2], sv2[16], sb1[16];
  int t = threadIdx.x;
  if (t < 32) sW2[t] = W2bu_s[t];
  if (t < 2) sa2[t] = a2bu_s[t];
  if (t < 16) {
    float s = 0.f;
    for (int cc = 0; cc < 2; ++cc) s += W2ub_d[t * 2 + cc] * a2ub_d[cc];
    sv2[t] = s;
    sb1[t] = b1ub[t];
  }
  __syncthreads();
  int n = blockIdx.x * 256 + t;
  if (n >= NB) return;
  float a[16];
#pragma unroll
  for (int c = 0; c < 16; ++c) a[c] = 0.f;
  float se = 0.f;
  for (int s = 0; s < 4; ++s) {
    const float4* p = (const float4*)(acc_sl + ((size_t)s * NB + n) * 16);
    float4 v0 = p[0], v1 = p[1], v2 = p[2], v3 = p[3];
    a[0] += v0.x; a[1] += v0.y; a[2] += v0.z; a[3] += v0.w;
    a[4] += v1.x; a[5] += v1.y; a[6] += v1.z; a[7] += v1.w;
    a[8] += v2.x; a[9] += v2.y; a[10] += v2.z; a[11] += v2.w;
    a[12] += v3.x; a[13] += v3.y; a[14] += v3.z; a[15] += v3.w;
    se += se_sl[s * NB + n];
  }
  float inv = 1.f / (se + 1e-16f);
  float h0 = 0.f, h1 = 0.f, advn = 0.f;
#pragma unroll
  for (int c = 0; c < 16; ++c) {
    float xv = fmaxf(a[c] * inv + sb1[c], 0.f);
    h0 += xv * sW2[c * 2];
    h1 += xv * sW2[c * 2 + 1];
    advn += xv * sv2[c];
  }
  pk_b[n] = make_float4(h0 * sa2[0] + h1 * sa2[1], h0, h1, advn);
}

// ---------------- fused layer-2 output gathers (packed tables, 4-lane groups, 2-stage pipeline) ----------------
__global__ void k_gatherL2(
    const int* __restrict__ rp0, const int* __restrict__ col0,
    const int* __restrict__ rp1, const int* __restrict__ col1,
    const float4* __restrict__ pk_u, const float4* __restrict__ pk_b,
    const float* __restrict__ b2ub, const float* __restrict__ b2bu,
    float* __restrict__ ob, float* __restrict__ ou,
    int NB, int NU, int g0) {
  int blk = blockIdx.x;
  const int *rp, *col; const float4 *pksrc, *pkown; const float* bb; float* out;
  int N, lsh, nsg;
  if (blk < g0) { rp = rp0; col = col0; pksrc = pk_u; pkown = pk_b; bb = b2ub;
                  out = ob; N = NB; lsh = 7; nsg = 4; }
  else { blk -= g0; rp = rp1; col = col1; pksrc = pk_b; pkown = pk_u; bb = b2bu;
         out = ou; N = NU; lsh = 9; nsg = 1; }
  int n = blk * 64 + (threadIdx.x >> 2);
  int j = threadIdx.x & 3;
  if (n >= N) return;
  int base = (n >> lsh) * 513 + (n & ((1 << lsh) - 1)) * nsg;
  int beg = rp[base], end = rp[base + nsg];
  float adv = pkown[n].w;
  float a0 = 0.f, a1 = 0.f, se = 0.f;
  // stride-4 coalesced, 2-stage pipeline (payload for i+1 issued before
  // consuming i; col prefetched for i+2)
  int k0 = beg + j;
  if (k0 < end) {
    int c0 = col[k0];
    int k1 = k0 + 4;
    int c1 = (k1 < end) ? col[k1] : -1;
    float4 p0 = pksrc[c0];
    for (;;) {
      float4 p1 = p0;
      int c2 = -1;
      int k2 = k1 + 4;
      if (c1 >= 0) {
        p1 = pksrc[c1];
        c2 = (k2 < end) ? col[k2] : -1;
      }
      float w = __expf(lrelu(p0.x + adv));
      se += w;
      a0 += w * p0.y;
      a1 += w * p0.z;
      if (c1 < 0) break;
      p0 = p1;
      c1 = c2;
      k1 = k2;
    }
  }
#pragma unroll
  for (int m = 1; m < 4; m <<= 1) {
    se += __shfl_xor(se, m, 4);
    a0 += __shfl_xor(a0, m, 4);
    a1 += __shfl_xor(a1, m, 4);
  }
  if (j == 0) {
    float inv = 1.f / (se + 1e-16f);
    out[(size_t)n * 2] = a0 * inv + bb[0];
    out[(size_t)n * 2 + 1] = a1 * inv + bb[1];
  }
}

extern "C" void kernel_launch(void* const* d_in, const int* in_sizes, int n_in,
                              void* d_out, int out_size, void* d_ws, size_t ws_size,
                              hipStream_t stream) {
  const int NU = 200000, NB = 50000;
  const float* x_user  = (const float*)d_in[0];
  const float* x_badge = (const float*)d_in[1];
  const int* ub_src = (const int*)d_in[2];
  const int* ub_dst = (const int*)d_in[3];
  const int* bu_src = (const int*)d_in[4];
  const int* bu_dst = (const int*)d_in[5];
  const int nE = in_sizes[2];

  const float* W1_ub_s = (const float*)d_in[8];
  const float* W1_ub_d = (const float*)d_in[9];
  const float* a1_ub_s = (const float*)d_in[10];
  const float* a1_ub_d = (const float*)d_in[11];
  const float* b1_ub   = (const float*)d_in[12];
  const float* W2_ub_s = (const float*)d_in[13];
  const float* W2_ub_d = (const float*)d_in[14];
  const float* a2_ub_s = (const float*)d_in[15];
  const float* a2_ub_d = (const float*)d_in[16];
  const float* b2_ub   = (const float*)d_in[17];
  const float* W1_bu_s = (const float*)d_in[18];
  const float* W1_bu_d = (const float*)d_in[19];
  const float* a1_bu_s = (const float*)d_in[20];
  const float* a1_bu_d = (const float*)d_in[21];
  const float* b1_bu   = (const float*)d_in[22];
  const float* W2_bu_s = (const float*)d_in[23];
  const float* W2_bu_d = (const float*)d_in[24];
  const float* a2_bu_s = (const float*)d_in[25];
  const float* a2_bu_d = (const float*)d_in[26];
  const float* b2_bu   = (const float*)d_in[27];

  const int pblocks = (nE + PART_PER - 1) / PART_PER;
  const int gNU = (NU + 255) / 256;        // 782
  const int gNB = (NB + 255) / 256;        // 196

  // ---- workspace carve-up ----
  char* wsb = (char*)d_ws;
  size_t off = 0;
  auto ialloc = [&](size_t n) { int* p = (int*)(wsb + off); off += n * 4; return p; };
  int* rp2_ub = ialloc((size_t)NHALF * 513);
  int* rp2_bu = ialloc((size_t)NHALF * 513);
  int* bcnt   = ialloc(512);
  int* col_ub = ialloc((size_t)NHALF * CAPH);
  int* col_bu = ialloc((size_t)NHALF * CAPH);
  off = (off + 15) & ~(size_t)15;
  const size_t partBytes = (size_t)2 * NBC * CAPC * 4;
  const size_t nodeBytes = (size_t)NU * 32 + (size_t)NB * 32 +
                           (size_t)(NU + NB) * 8 + 1024;
  bool fused = ws_size >= off + partBytes + nodeBytes + 4096;
  char* partBase = wsb + off;
  char* nodeBase = fused ? (partBase + partBytes) : partBase;
  unsigned* part0 = (unsigned*)partBase;
  unsigned* part1 = part0 + (size_t)NBC * CAPC;
  size_t poff = 0;
  auto falloc = [&](size_t n) { float* p = (float*)(nodeBase + poff); poff += n * 4; return p; };
  auto halloc = [&](size_t n) { __half* p = (__half*)(nodeBase + poff); poff += n * 2; return p; };
  __half* hs_u1 = halloc((size_t)NU * 16);
  __half* hs_b1 = halloc((size_t)NB * 16);
  float* as_u1  = falloc(NU);
  float* ad_u1  = falloc(NU);
  float* as_b1  = falloc(NB);
  float* ad_b1  = falloc(NB);
  poff = (poff + 15) & ~(size_t)15;
  float4* pk_u  = (float4*)(nodeBase + poff); poff += (size_t)NU * 16;
  float4* pk_b  = (float4*)(nodeBase + poff); poff += (size_t)NB * 16;
  char* accBase = fused ? partBase : (nodeBase + ((poff + 15) & ~(size_t)15));
  float* acc_sl = (float*)accBase;
  float* se_sl  = (float*)(accBase + (size_t)4 * NB * 16 * 4);

  float* ou = (float*)d_out;                   // [NU,2]
  float* ob = (float*)d_out + (size_t)NU * 2;  // [NB,2]

  // megaL1: 8-lane paired groups -> 32 nodes per 256-thread block
  const int chunksB = (NB + 31) / 32;                 // 1563
  const int ubBlocks = ((chunksB + 1) / 2) * 8;       // 6256 (xcd-pinned pairs)
  const int buBlocks = (NU + 31) / 32;                // 6250
  // gatherL2: 4-lane groups -> 64 nodes per block
  const int g0 = (NB + 63) / 64;                      // 782
  const int g1 = (NU + 63) / 64;                      // 3125

  hipMemsetAsync(bcnt, 0, 512 * 4, stream);
  if (fused) {
    k_stageA<<<dim3(2 * pblocks + gNU + gNB), dim3(256), 0, stream>>>(
        ub_src, ub_dst, bu_src, bu_dst, nE, pblocks, part0, part1, bcnt,
        x_user, x_badge, W1_ub_s, a1_ub_s, W1_bu_d, a1_bu_d,
        W1_bu_s, a1_bu_s, W1_ub_d, a1_ub_d,
        hs_u1, as_u1, ad_u1, hs_b1, as_b1, ad_b1, NU, NB, gNU,
        2 * pblocks, gNU + gNB);
    k_sort2_both<<<dim3(2 * NHALF), dim3(512), 0, stream>>>(
        part0, part1, bcnt, col_ub, col_bu, rp2_ub, rp2_bu);
  } else {
    k_stageA<<<dim3(2 * pblocks), dim3(256), 0, stream>>>(
        ub_src, ub_dst, bu_src, bu_dst, nE, pblocks, part0, part1, bcnt,
        x_user, x_badge, W1_ub_s, a1_ub_s, W1_bu_d, a1_bu_d,
        W1_bu_s, a1_bu_s, W1_ub_d, a1_ub_d,
        hs_u1, as_u1, ad_u1, hs_b1, as_b1, ad_b1, NU, NB, gNU,
        2 * pblocks, 0);
    k_sort2_both<<<dim3(2 * NHALF), dim3(512), 0, stream>>>(
        part0, part1, bcnt, col_ub, col_bu, rp2_ub, rp2_bu);
    k_stageA<<<dim3(gNU + gNB), dim3(256), 0, stream>>>(
        ub_src, ub_dst, bu_src, bu_dst, nE, pblocks, part0, part1, bcnt,
        x_user, x_badge, W1_ub_s, a1_ub_s, W1_bu_d, a1_bu_d,
        W1_bu_s, a1_bu_s, W1_ub_d, a1_ub_d,
        hs_u1, as_u1, ad_u1, hs_b1, as_b1, ad_b1, NU, NB, gNU,
        0, gNU + gNB);
  }
  k_megaL1<<<dim3(ubBlocks + buBlocks), dim3(256), 0, stream>>>(
      rp2_ub, col_ub, a1_ub_s, ad_b1, hs_u1, acc_sl, se_sl,
      rp2_bu, col_bu, a1_bu_s, ad_u1, hs_b1,
      b1_bu, W2_ub_s, a2_ub_s, W2_bu_d, a2_bu_d,
      pk_u, NB, NU, ubBlocks);
  k_finL1b<<<dim3(gNB), dim3(256), 0, stream>>>(
      acc_sl, se_sl, b1_ub, W2_bu_s, a2_bu_s, W2_ub_d, a2_ub_d, pk_b, NB);
  k_gatherL2<<<dim3(g0 + g1), dim3(256), 0, stream>>>(
      rp2_ub, col_ub, rp2_bu, col_bu, pk_u, pk_b, b2_ub, b2_bu, ob, ou, NB, NU, g0);
}